// Round 11
// baseline (1052.727 us; speedup 1.0000x reference)
//
#include <hip/hip_runtime.h>
#include <hip/hip_bf16.h>

#define B_ 2
#define S_ 2048
#define D_ 512
#define H_ 8
#define L_ 6
#define F_ 2048
#define HD_ 64
#define M_ 4096
#define OFF_ 4999
#define NREL_ 9999

typedef short s8v __attribute__((ext_vector_type(8)));
typedef float f4v __attribute__((ext_vector_type(4)));

enum { MODE_BF16 = 0, MODE_RES = 1, MODE_GELU = 2 };

__device__ __forceinline__ short f2bf(float f) {
  unsigned u = __float_as_uint(f);
  unsigned r = (u + 0x7fffu + ((u >> 16) & 1u)) >> 16;
  return (short)r;
}

__device__ __forceinline__ float exp2fast(float x) {
  float r;
  asm("v_exp_f32 %0, %1" : "=v"(r) : "v"(x));
  return r;
}

__device__ __forceinline__ int cvt_pk_bf16(float lo, float hi) {
  int r;
  asm("v_cvt_pk_bf16_f32 %0, %1, %2" : "=v"(r) : "v"(lo), "v"(hi));
  return r;
}

__device__ __forceinline__ void gload16(const void* g, const void* l) {
  __builtin_amdgcn_global_load_lds((const __attribute__((address_space(1))) unsigned int*)g,
                                   (__attribute__((address_space(3))) unsigned int*)l,
                                   16, 0, 0);
}

// ---------------- weight transpose: src fp32 (K,N) -> dst bf16 (N,K) -------
__global__ void transpose_kernel(const float* __restrict__ src, short* __restrict__ dst,
                                 int K, int N, long srcBS, long dstBS, int rowOff)
{
  __shared__ float t[32][33];
  int tx = threadIdx.x, ty = threadIdx.y;  // block (32,8)
  int n0 = blockIdx.x * 32, k0 = blockIdx.y * 32, l = blockIdx.z;
  const float* s = src + (size_t)l * srcBS;
  short* d = dst + (size_t)l * dstBS;
  for (int j = 0; j < 4; ++j)
    t[ty + j*8][tx] = s[(size_t)(k0 + ty + j*8) * N + n0 + tx];
  __syncthreads();
  for (int j = 0; j < 4; ++j)
    d[(size_t)(rowOff + n0 + ty + j*8) * K + k0 + tx] = f2bf(t[tx][ty + j*8]);
}

__global__ void packb_kernel(const float* __restrict__ bq, const float* __restrict__ bk,
                             const float* __restrict__ bv, float* __restrict__ bqkv)
{
  int i = blockIdx.x * 256 + threadIdx.x;
  if (i >= L_ * 1536) return;
  int l = i / 1536, j = i % 1536;
  float v = (j < 512) ? bq[l*512 + j] : (j < 1024) ? bk[l*512 + j - 512] : bv[l*512 + j - 1024];
  bqkv[i] = v;
}

// ---- bias table transpose + pre-scale by log2(e): exp2-domain softmax -----
__global__ void tabt_kernel(const float* __restrict__ tab, float* __restrict__ tabT)
{
  int i = blockIdx.x * 256 + threadIdx.x;
  if (i >= L_ * H_ * NREL_) return;
  int l = i / (H_ * NREL_), rem = i % (H_ * NREL_);
  int h = rem / NREL_, idx = rem % NREL_;
  tabT[i] = tab[((size_t)l * NREL_ + idx) * H_ + h] * 1.44269504f;
}

// ---------------- spk_emb @ Wspk + bspk: grid (B_, 8), k-split + LDS reduce -
__global__ __launch_bounds__(256) void spk_kernel(const float* __restrict__ spk,
                                                  const float* __restrict__ Wspk,
                                                  const float* __restrict__ bspk,
                                                  float* __restrict__ sproj)
{
  __shared__ float red[4][64];
  int b = blockIdx.x, nb = blockIdx.y;
  int dl = threadIdx.x & 63, kc = threadIdx.x >> 6;
  int d = nb * 64 + dl;
  const float* sprow = spk + b * D_;
  float a0 = 0.f, a1 = 0.f;
  int kbeg = kc * 128;
  for (int k = kbeg; k < kbeg + 128; k += 2) {
    a0 += sprow[k]     * Wspk[(size_t)k * D_ + d];
    a1 += sprow[k + 1] * Wspk[(size_t)(k + 1) * D_ + d];
  }
  red[kc][dl] = a0 + a1;
  __syncthreads();
  if (kc == 0)
    sproj[b*D_ + d] = red[0][dl] + red[1][dl] + red[2][dl] + red[3][dl] + bspk[d];
}

// ---------------- prologue: x + PE + cond encodings -> X fp32 --------------
__global__ __launch_bounds__(256) void prologue_kernel(
    const float* __restrict__ x, const float* __restrict__ f0, const float* __restrict__ sp,
    const float* __restrict__ ap, const float* __restrict__ Wf0, const float* __restrict__ bf0,
    const float* __restrict__ Wsp, const float* __restrict__ bsp,
    const float* __restrict__ Wap, const float* __restrict__ bap,
    const float* __restrict__ sproj, float* __restrict__ X)
{
  int row = blockIdx.x, tid = threadIdx.x;
  int b = row >> 11, s = row & 2047;
  float vf0 = f0[row], vsp = sp[row], vap = ap[row];
  for (int j = 0; j < 2; ++j) {
    int d = tid + j * 256;
    int i = d >> 1;
    float div = expf((float)(2*i) * -0.01798894603f);  // -ln(10000)/512
    float arg = (float)s * div;
    float pe = (d & 1) ? cosf(arg) : sinf(arg);
    float v = x[(size_t)row*D_ + d] + pe
            + vf0*Wf0[d] + bf0[d] + vsp*Wsp[d] + bsp[d] + vap*Wap[d] + bap[d]
            + sproj[b*D_ + d];
    X[(size_t)row*D_ + d] = v;
  }
}

// ---------------- layernorm: X fp32 row -> bf16 (or fp32 final) ------------
__global__ __launch_bounds__(256) void ln_kernel(
    const float* __restrict__ X, const float* __restrict__ g, const float* __restrict__ bta,
    short* __restrict__ outB, float* __restrict__ outF, int f32out)
{
  __shared__ float red[8];
  int row = blockIdx.x, tid = threadIdx.x;
  const float* xr = X + (size_t)row * D_;
  float v0 = xr[tid], v1 = xr[tid + 256];
  float s = v0 + v1, q = v0*v0 + v1*v1;
  for (int off = 1; off < 64; off <<= 1) { s += __shfl_xor(s, off); q += __shfl_xor(q, off); }
  int w = tid >> 6;
  if ((tid & 63) == 0) { red[w*2] = s; red[w*2 + 1] = q; }
  __syncthreads();
  s = red[0] + red[2] + red[4] + red[6];
  q = red[1] + red[3] + red[5] + red[7];
  float mean = s * (1.0f / D_);
  float var = q * (1.0f / D_) - mean * mean;
  float rstd = rsqrtf(var + 1e-5f);
  float o0 = (v0 - mean) * rstd * g[tid] + bta[tid];
  float o1 = (v1 - mean) * rstd * g[tid + 256] + bta[tid + 256];
  if (f32out) {
    outF[(size_t)row*D_ + tid] = o0; outF[(size_t)row*D_ + tid + 256] = o1;
  } else {
    outB[(size_t)row*D_ + tid] = f2bf(o0); outB[(size_t)row*D_ + tid + 256] = f2bf(o1);
  }
}

// ---------------- bf16 MFMA GEMM (round-21: 128x128 tile) ------------------
// Round-20 analysis: non-flash budget ~128us/layer; 51.6 GFLOP/layer of GEMM
// implies ~450-550 TF with the old 128x64 tile. Tile ladder (m92->m103) says
// 128x128 + 4x8 acc is the 2-barrier structure's sweet spot (912 TF class):
// per-MFMA LDS traffic 768->640B, B-panel HBM amortizes over 2x columns.
// Changes: sB 8->16KB (LDS 24->32KB), acc[2][4]->acc[2][8], 2nd B gload16
// pair, grid y halves (qkv 12, o 4, ffn1 16, ffn2 4). Epilogue logic same.
// Grid: x = m-block (32, 128 rows each), y = n-block (128 cols), z = split-K.
// gridDim.x = 32 == 0 mod 8 -> A-slice stays XCD-local (same m -> same XCD).
template<int MODE>
__device__ __forceinline__ void gemm_body(
    const short* __restrict__ A, const short* __restrict__ Wt,
    const float* __restrict__ bias, int K, int N,
    float* outF, short* outB)
{
  __shared__ short sA[2][4096];  // [panel][128 rows][32 k]
  __shared__ short sB[2][4096];  // [panel][128 rows][32 k]
  const int tid = threadIdx.x;
  const int w = tid >> 6, lane = tid & 63;
  const int col = lane & 15, quad = lane >> 4;
  const int m0 = blockIdx.x * 128, n0 = blockIdx.y * 128;
  const int z = blockIdx.z;
  const int Ksub = K / gridDim.z;
  const int kbase = z * Ksub;
  const int nkt = Ksub >> 6;

  const int rowT = tid >> 2, kcA = tid & 3;
  const size_t kc8 = kcA * 8;

  f4v acc[2][8] = {};
  for (int kt = 0; kt < nkt; ++kt) {
    const int k0 = kbase + kt * 64;
    __syncthreads();
    for (int p = 0; p < 2; ++p) {
      gload16(A + (size_t)(m0 + rowT) * K + k0 + p*32 + kc8,        &sA[p][(w*16) * 32]);
      gload16(A + (size_t)(m0 + 64 + rowT) * K + k0 + p*32 + kc8,   &sA[p][(64 + w*16) * 32]);
      gload16(Wt + (size_t)(n0 + rowT) * K + k0 + p*32 + kc8,       &sB[p][(w*16) * 32]);
      gload16(Wt + (size_t)(n0 + 64 + rowT) * K + k0 + p*32 + kc8,  &sB[p][(64 + w*16) * 32]);
    }
    __syncthreads();
    for (int p = 0; p < 2; ++p) {
      s8v af[2], bfr[8];
      #pragma unroll
      for (int mt = 0; mt < 2; ++mt)
        af[mt] = *(const s8v*)&sA[p][(w*32 + mt*16 + col) * 32 + quad * 8];
      #pragma unroll
      for (int nt = 0; nt < 8; ++nt)
        bfr[nt] = *(const s8v*)&sB[p][(nt*16 + col) * 32 + quad * 8];
      #pragma unroll
      for (int mt = 0; mt < 2; ++mt)
        #pragma unroll
        for (int nt = 0; nt < 8; ++nt)
          acc[mt][nt] = __builtin_amdgcn_mfma_f32_16x16x32_bf16(af[mt], bfr[nt], acc[mt][nt], 0, 0, 0);
    }
  }

  const float qscQ = (MODE == MODE_BF16) ? 0.18033688f : 1.0f;  // 0.125*log2e
  float bz[8];
  #pragma unroll
  for (int nt = 0; nt < 8; ++nt)
    bz[nt] = (z == 0) ? bias[n0 + nt*16 + col] : 0.0f;
  #pragma unroll
  for (int mt = 0; mt < 2; ++mt) {
    int mbase = m0 + w*32 + mt*16 + quad*4;
    #pragma unroll
    for (int nt = 0; nt < 8; ++nt) {
      int n = n0 + nt*16 + col;
      const float qsc = (MODE == MODE_BF16 && n < 512) ? qscQ : 1.0f;
      #pragma unroll
      for (int r = 0; r < 4; ++r) {
        float v = acc[mt][nt][r] + bz[nt];
        size_t idx = (size_t)(mbase + r) * N + n;
        if (MODE == MODE_RES) {
          atomicAdd(outF + idx, v);
        } else if (MODE == MODE_GELU) {
          outB[idx] = f2bf(0.5f * v * (1.0f + erff(v * 0.70710678118f)));
        } else {
          outB[idx] = f2bf(v * qsc);
        }
      }
    }
  }
}

__global__ __launch_bounds__(256) void gemm_qkv_kernel(
    const short* __restrict__ A, const short* __restrict__ Wt,
    const float* __restrict__ bias, float* outF, short* outB)
{ gemm_body<MODE_BF16>(A, Wt, bias, 512, 1536, outF, outB); }

__global__ __launch_bounds__(256) void gemm_o_kernel(
    const short* __restrict__ A, const short* __restrict__ Wt,
    const float* __restrict__ bias, float* outF, short* outB)
{ gemm_body<MODE_RES>(A, Wt, bias, 512, 512, outF, outB); }

__global__ __launch_bounds__(256) void gemm_ffn1_kernel(
    const short* __restrict__ A, const short* __restrict__ Wt,
    const float* __restrict__ bias, float* outF, short* outB)
{ gemm_body<MODE_GELU>(A, Wt, bias, 512, 2048, outF, outB); }

__global__ __launch_bounds__(256) void gemm_ffn2_kernel(
    const short* __restrict__ A, const short* __restrict__ Wt,
    const float* __restrict__ bias, float* outF, short* outB)
{ gemm_body<MODE_RES>(A, Wt, bias, 2048, 512, outF, outB); }

// ---------------- V transpose: QKV V-part (b,s,h,hd) -> Vt (b,h,hd,s) ------
__global__ __launch_bounds__(256) void vtrans_kernel(const short* __restrict__ QKV,
                                                     short* __restrict__ Vt)
{
  __shared__ short t[64 * 72];
  int tid = threadIdx.x;
  int s0 = blockIdx.x * 64, bh = blockIdx.y;
  int b = bh >> 3, h = bh & 7;
  for (int it = 0; it < 2; ++it) {
    int c = it * 256 + tid;
    int sR = c >> 3, hc = c & 7;
    s8v v = *(const s8v*)(QKV + (size_t)(b*S_ + s0 + sR) * 1536 + 1024 + h*64 + hc*8);
    *(s8v*)&t[sR * 72 + hc * 8] = v;
  }
  __syncthreads();
  for (int it = 0; it < 2; ++it) {
    int c = it * 256 + tid;
    int hd = c >> 3, sc = c & 7;
    s8v v;
    for (int j = 0; j < 8; ++j) v[j] = t[(sc*8 + j) * 72 + hd];
    *(s8v*)(Vt + (size_t)(bh*64 + hd) * S_ + s0 + sc*8) = v;
  }
}

// ---------------- flash attention v9 (verified round-20: 40.2us, passed) ---
// Byte-identical to the round-20 kernel for clean attribution of this
// round's GEMM change. Bias per-lane from global (idx range [2952,7046]),
// direct-Q, cvt_pk P-pack; sK/sV LDS broadcast staging.
#define SM_MT(ko, mt, ST, Bb0, Bb1, Bb2, Bb3) do {                  \
    float p0 = exp2fast(ST[0] + Bb0);                               \
    float p1 = exp2fast(ST[1] + Bb1);                               \
    float p2 = exp2fast(ST[2] + Bb2);                               \
    float p3 = exp2fast(ST[3] + Bb3);                               \
    lsum += (p0 + p1) + (p2 + p3);                                  \
    int2 pk;                                                        \
    pk.x = cvt_pk_bf16(p0, p1);                                     \
    pk.y = cvt_pk_bf16(p2, p3);                                     \
    *(int2*)&sP[w*1280 + (ko)*640 + col*40 + (mt)*16 + quad*4] = pk;\
  } while (0)

#define KOBLOCK(ko, B0a,B0b,B0c,B0d, B1a,B1b,B1c,B1d) do {                         \
    f4v st0 = {}, st1 = {};                                                        \
    s8v a00 = *(const s8v*)&sK[(ko)*2560 + 0*1280 + (0*16 + col)*40 + quad*8];     \
    s8v a01 = *(const s8v*)&sK[(ko)*2560 + 1*1280 + (0*16 + col)*40 + quad*8];     \
    s8v a10 = *(const s8v*)&sK[(ko)*2560 + 0*1280 + (1*16 + col)*40 + quad*8];     \
    s8v a11 = *(const s8v*)&sK[(ko)*2560 + 1*1280 + (1*16 + col)*40 + quad*8];     \
    st0 = __builtin_amdgcn_mfma_f32_16x16x32_bf16(a00, bQ0, st0, 0, 0, 0);         \
    st0 = __builtin_amdgcn_mfma_f32_16x16x32_bf16(a01, bQ1, st0, 0, 0, 0);         \
    st1 = __builtin_amdgcn_mfma_f32_16x16x32_bf16(a10, bQ0, st1, 0, 0, 0);         \
    st1 = __builtin_amdgcn_mfma_f32_16x16x32_bf16(a11, bQ1, st1, 0, 0, 0);         \
    SM_MT(ko, 0, st0, B0a,B0b,B0c,B0d);                                            \
    SM_MT(ko, 1, st1, B1a,B1b,B1c,B1d);                                            \
    s8v aP = *(const s8v*)&sP[w*1280 + (ko)*640 + col*40 + quad*8];                \
    s8v v0 = *(const s8v*)&sV[(ko)*2560 + ( 0 + col)*40 + quad*8];                 \
    s8v v1 = *(const s8v*)&sV[(ko)*2560 + (16 + col)*40 + quad*8];                 \
    s8v v2 = *(const s8v*)&sV[(ko)*2560 + (32 + col)*40 + quad*8];                 \
    s8v v3 = *(const s8v*)&sV[(ko)*2560 + (48 + col)*40 + quad*8];                 \
    o0 = __builtin_amdgcn_mfma_f32_16x16x32_bf16(aP, v0, o0, 0, 0, 0);             \
    o1 = __builtin_amdgcn_mfma_f32_16x16x32_bf16(aP, v1, o1, 0, 0, 0);             \
    o2 = __builtin_amdgcn_mfma_f32_16x16x32_bf16(aP, v2, o2, 0, 0, 0);             \
    o3 = __builtin_amdgcn_mfma_f32_16x16x32_bf16(aP, v3, o3, 0, 0, 0);             \
  } while (0)

__global__ __launch_bounds__(512) void flash_kernel(
    const short* __restrict__ QKV, const short* __restrict__ Vt,
    const float* __restrict__ tabT, short* __restrict__ AO)
{
  __shared__ __attribute__((aligned(16))) short sK[2 * 2 * 32 * 40];  // [ko][hc][kk][40]
  __shared__ __attribute__((aligned(16))) short sV[2 * 64 * 40];      // [ko][hd][40]
  __shared__ __attribute__((aligned(16))) short sP[8 * 2 * 16 * 40];  // [w][ko][q][40]
  __shared__ float sRow[8 * 16];

  const int tid = threadIdx.x;
  const int w = tid >> 6, lane = tid & 63;
  const int col = lane & 15, quad = lane >> 4;
  const int bh = blockIdx.x, qt = blockIdx.y;
  const int b = bh >> 3, h = bh & 7;
  const int q0 = qt * 128;
  const int wq = w * 16;
  const int nkt = S_ / 64;
  const float* tabh = tabT + (size_t)h * NREL_;
  // per-lane bias base: element (kt*64 + ko*32 + mt*16 + j) relative to this
  const float* tbL = tabh + (OFF_ - q0 + quad*4 - wq - col);

  // Q fragments direct from global (one 16B load per lane per hc)
  const short* gQ = QKV + (size_t)(b*S_ + q0 + wq + col) * 1536 + h*64 + quad*8;
  s8v bQ0 = *(const s8v*)gQ;
  s8v bQ1 = *(const s8v*)(gQ + 32);

  const int c4 = tid & 3;
  const int kK = (tid >> 2) & 63, hcK = tid >> 8;
  const short* gK = QKV + (size_t)(b*S_ + kK) * 1536 + 512 + h*64 + hcK*32 + c4*8;
  short* dK = &sK[(kK >> 5)*2560 + hcK*1280 + (kK & 31)*40 + c4*8];
  const int c8 = tid & 7, hdV = tid >> 3;
  const short* gV = Vt + (size_t)(bh*64 + hdV) * S_ + c8*8;
  short* dV = &sV[(c8 >> 2)*2560 + hdV*40 + (c8 & 3)*8];

  int4 rk = *(const int4*)gK;
  int4 rv = *(const int4*)gV;

  float lsum = 0.0f;
  f4v o0 = {}, o1 = {}, o2 = {}, o3 = {};

  for (int kt = 0; kt < nkt; ++kt) {
    // bias fetch for this tile (global, L2-hot): issued before both barriers
    const float* tb = tbL + kt * 64;
    float bA0 = tb[0],  bA1 = tb[1],  bA2 = tb[2],  bA3 = tb[3];
    float bB0 = tb[16], bB1 = tb[17], bB2 = tb[18], bB3 = tb[19];
    float bC0 = tb[32], bC1 = tb[33], bC2 = tb[34], bC3 = tb[35];
    float bD0 = tb[48], bD1 = tb[49], bD2 = tb[50], bD3 = tb[51];
    __syncthreads();
    *(int4*)dK = rk;
    *(int4*)dV = rv;
    __syncthreads();
    if (kt + 1 < nkt) {
      rk = *(const int4*)(gK + (size_t)(kt + 1) * 64 * 1536);
      rv = *(const int4*)(gV + (kt + 1) * 64);
    }
    KOBLOCK(0, bA0, bA1, bA2, bA3, bB0, bB1, bB2, bB3);
    KOBLOCK(1, bC0, bC1, bC2, bC3, bD0, bD1, bD2, bD3);
  }

  lsum += __shfl_xor(lsum, 16);
  lsum += __shfl_xor(lsum, 32);
  if (lane < 16) sRow[w*16 + lane] = lsum;
  float rs0 = sRow[w*16 + quad*4 + 0];
  float rs1 = sRow[w*16 + quad*4 + 1];
  float rs2 = sRow[w*16 + quad*4 + 2];
  float rs3 = sRow[w*16 + quad*4 + 3];
  size_t mrow = (size_t)(b*S_ + q0 + wq + quad*4);
  short* aoBase = AO + mrow * 512 + h*64 + col;
  aoBase[0*512 +  0] = f2bf(o0[0] / rs0);
  aoBase[1*512 +  0] = f2bf(o0[1] / rs1);
  aoBase[2*512 +  0] = f2bf(o0[2] / rs2);
  aoBase[3*512 +  0] = f2bf(o0[3] / rs3);
  aoBase[0*512 + 16] = f2bf(o1[0] / rs0);
  aoBase[1*512 + 16] = f2bf(o1[1] / rs1);
  aoBase[2*512 + 16] = f2bf(o1[2] / rs2);
  aoBase[3*512 + 16] = f2bf(o1[3] / rs3);
  aoBase[0*512 + 32] = f2bf(o2[0] / rs0);
  aoBase[1*512 + 32] = f2bf(o2[1] / rs1);
  aoBase[2*512 + 32] = f2bf(o2[2] / rs2);
  aoBase[3*512 + 32] = f2bf(o2[3] / rs3);
  aoBase[0*512 + 48] = f2bf(o3[0] / rs0);
  aoBase[1*512 + 48] = f2bf(o3[1] / rs1);
  aoBase[2*512 + 48] = f2bf(o3[2] / rs2);
  aoBase[3*512 + 48] = f2bf(o3[3] / rs3);
}

// ===========================================================================
extern "C" void kernel_launch(void* const* d_in, const int* in_sizes, int n_in,
                              void* d_out, int out_size, void* d_ws, size_t ws_size,
                              hipStream_t stream)
{
  const float* x    = (const float*)d_in[0];
  const float* f0   = (const float*)d_in[1];
  const float* sp   = (const float*)d_in[2];
  const float* ap   = (const float*)d_in[3];
  const float* spk  = (const float*)d_in[4];
  const float* Wf0  = (const float*)d_in[5];  const float* bf0  = (const float*)d_in[6];
  const float* Wsp  = (const float*)d_in[7];  const float* bsp  = (const float*)d_in[8];
  const float* Wap  = (const float*)d_in[9];  const float* bap  = (const float*)d_in[10];
  const float* Wspk = (const float*)d_in[11]; const float* bspk = (const float*)d_in[12];
  const float* Wq   = (const float*)d_in[13]; const float* bq   = (const float*)d_in[14];
  const float* Wk   = (const float*)d_in[15]; const float* bk   = (const float*)d_in[16];
  const float* Wv   = (const float*)d_in[17]; const float* bv   = (const float*)d_in[18];
  const float* Wo   = (const float*)d_in[19]; const float* bo   = (const float*)d_in[20];
  const float* ln1g = (const float*)d_in[21]; const float* ln1b = (const float*)d_in[22];
  const float* ln2g = (const float*)d_in[23]; const float* ln2b = (const float*)d_in[24];
  const float* W1   = (const float*)d_in[25]; const float* b1   = (const float*)d_in[26];
  const float* W2   = (const float*)d_in[27]; const float* b2   = (const float*)d_in[28];
  const float* tab  = (const float*)d_in[29];
  const float* gfin = (const float*)d_in[30]; const float* bfin = (const float*)d_in[31];

  char* p = (char*)d_ws;
  auto alloc = [&](size_t bytes) { char* r = p; p += (bytes + 255) & ~(size_t)255; return r; };
  short* WqkvT = (short*)alloc((size_t)L_ * 1536 * 512 * 2);
  short* WoT   = (short*)alloc((size_t)L_ * 512 * 512 * 2);
  short* W1T   = (short*)alloc((size_t)L_ * 2048 * 512 * 2);
  short* W2T   = (short*)alloc((size_t)L_ * 512 * 2048 * 2);
  float* bqkv  = (float*)alloc((size_t)L_ * 1536 * 4);
  float* X     = (float*)alloc((size_t)M_ * D_ * 4);
  short* Hb    = (short*)alloc((size_t)M_ * D_ * 2);
  short* AO    = (short*)alloc((size_t)M_ * D_ * 2);
  short* QKVb  = (short*)alloc((size_t)M_ * 1536 * 2);
  short* VtG   = (short*)alloc((size_t)B_ * H_ * HD_ * S_ * 2);
  short* H1b   = QKVb;  // alias: FFN hidden (M,F) reuses QKVb+VtG region (exactly 16 MB)
  float* sproj = (float*)alloc((size_t)B_ * D_ * 4);
  float* tabT  = (float*)alloc((size_t)L_ * H_ * NREL_ * 4);

  dim3 b256(256);
  dim3 tb(32, 8);
  packb_kernel<<<dim3((L_*1536 + 255)/256), b256, 0, stream>>>(bq, bk, bv, bqkv);
  tabt_kernel<<<dim3((L_*H_*NREL_ + 255)/256), b256, 0, stream>>>(tab, tabT);
  transpose_kernel<<<dim3(16, 16, L_), tb, 0, stream>>>(Wq, WqkvT, 512, 512, 512*512, 1536*512, 0);
  transpose_kernel<<<dim3(16, 16, L_), tb, 0, stream>>>(Wk, WqkvT, 512, 512, 512*512, 1536*512, 512);
  transpose_kernel<<<dim3(16, 16, L_), tb, 0, stream>>>(Wv, WqkvT, 512, 512, 512*512, 1536*512, 1024);
  transpose_kernel<<<dim3(16, 16, L_), tb, 0, stream>>>(Wo, WoT, 512, 512, 512*512, 512*512, 0);
  transpose_kernel<<<dim3(64, 16, L_), tb, 0, stream>>>(W1, W1T, 512, 2048, 512*2048, 2048*512, 0);
  transpose_kernel<<<dim3(16, 64, L_), tb, 0, stream>>>(W2, W2T, 2048, 512, 2048*512, 512*2048, 0);
  spk_kernel<<<dim3(B_, 8), b256, 0, stream>>>(spk, Wspk, bspk, sproj);
  prologue_kernel<<<dim3(M_), b256, 0, stream>>>(x, f0, sp, ap, Wf0, bf0, Wsp, bsp, Wap, bap, sproj, X);

  for (int l = 0; l < L_; ++l) {
    ln_kernel<<<dim3(M_), b256, 0, stream>>>(X, ln1g + l*D_, ln1b + l*D_, Hb, nullptr, 0);
    gemm_qkv_kernel<<<dim3(32, 12, 1), b256, 0, stream>>>(
        Hb, WqkvT + (size_t)l*1536*512, bqkv + l*1536, nullptr, QKVb);
    vtrans_kernel<<<dim3(S_/64, B_*H_), b256, 0, stream>>>(QKVb, VtG);
    flash_kernel<<<dim3(B_*H_, S_/128), dim3(512), 0, stream>>>(QKVb, VtG, tabT + (size_t)l*H_*NREL_, AO);
    gemm_o_kernel<<<dim3(32, 4, 2), b256, 0, stream>>>(
        AO, WoT + (size_t)l*512*512, bo + l*D_, X, nullptr);
    ln_kernel<<<dim3(M_), b256, 0, stream>>>(X, ln2g + l*D_, ln2b + l*D_, Hb, nullptr, 0);
    gemm_ffn1_kernel<<<dim3(32, 16, 1), b256, 0, stream>>>(
        Hb, W1T + (size_t)l*2048*512, b1 + l*F_, nullptr, H1b);
    gemm_ffn2_kernel<<<dim3(32, 4, 4), b256, 0, stream>>>(
        H1b, W2T + (size_t)l*512*2048, b2 + l*D_, X, nullptr);
  }
  ln_kernel<<<dim3(M_), b256, 0, stream>>>(X, gfin, bfin, nullptr, (float*)d_out, 1);
}

// Round 12
// 917.384 us; speedup vs baseline: 1.1475x; 1.1475x over previous
//
#include <hip/hip_runtime.h>
#include <hip/hip_bf16.h>

#define B_ 2
#define S_ 2048
#define D_ 512
#define H_ 8
#define L_ 6
#define F_ 2048
#define HD_ 64
#define M_ 4096
#define OFF_ 4999
#define NREL_ 9999

typedef short s8v __attribute__((ext_vector_type(8)));
typedef float f4v __attribute__((ext_vector_type(4)));

enum { MODE_BF16 = 0, MODE_RES = 1, MODE_GELU = 2 };

__device__ __forceinline__ short f2bf(float f) {
  unsigned u = __float_as_uint(f);
  unsigned r = (u + 0x7fffu + ((u >> 16) & 1u)) >> 16;
  return (short)r;
}

__device__ __forceinline__ float exp2fast(float x) {
  float r;
  asm("v_exp_f32 %0, %1" : "=v"(r) : "v"(x));
  return r;
}

__device__ __forceinline__ int cvt_pk_bf16(float lo, float hi) {
  int r;
  asm("v_cvt_pk_bf16_f32 %0, %1, %2" : "=v"(r) : "v"(lo), "v"(hi));
  return r;
}

__device__ __forceinline__ void gload16(const void* g, const void* l) {
  __builtin_amdgcn_global_load_lds((const __attribute__((address_space(1))) unsigned int*)g,
                                   (__attribute__((address_space(3))) unsigned int*)l,
                                   16, 0, 0);
}

// ---------------- weight transpose: src fp32 (K,N) -> dst bf16 (N,K) -------
__global__ void transpose_kernel(const float* __restrict__ src, short* __restrict__ dst,
                                 int K, int N, long srcBS, long dstBS, int rowOff)
{
  __shared__ float t[32][33];
  int tx = threadIdx.x, ty = threadIdx.y;  // block (32,8)
  int n0 = blockIdx.x * 32, k0 = blockIdx.y * 32, l = blockIdx.z;
  const float* s = src + (size_t)l * srcBS;
  short* d = dst + (size_t)l * dstBS;
  for (int j = 0; j < 4; ++j)
    t[ty + j*8][tx] = s[(size_t)(k0 + ty + j*8) * N + n0 + tx];
  __syncthreads();
  for (int j = 0; j < 4; ++j)
    d[(size_t)(rowOff + n0 + ty + j*8) * K + k0 + tx] = f2bf(t[tx][ty + j*8]);
}

__global__ void packb_kernel(const float* __restrict__ bq, const float* __restrict__ bk,
                             const float* __restrict__ bv, float* __restrict__ bqkv)
{
  int i = blockIdx.x * 256 + threadIdx.x;
  if (i >= L_ * 1536) return;
  int l = i / 1536, j = i % 1536;
  float v = (j < 512) ? bq[l*512 + j] : (j < 1024) ? bk[l*512 + j - 512] : bv[l*512 + j - 1024];
  bqkv[i] = v;
}

// ---- bias table transpose + pre-scale by log2(e): exp2-domain softmax -----
__global__ void tabt_kernel(const float* __restrict__ tab, float* __restrict__ tabT)
{
  int i = blockIdx.x * 256 + threadIdx.x;
  if (i >= L_ * H_ * NREL_) return;
  int l = i / (H_ * NREL_), rem = i % (H_ * NREL_);
  int h = rem / NREL_, idx = rem % NREL_;
  tabT[i] = tab[((size_t)l * NREL_ + idx) * H_ + h] * 1.44269504f;
}

// ---------------- spk_emb @ Wspk + bspk: grid (B_, 8), k-split + LDS reduce -
__global__ __launch_bounds__(256) void spk_kernel(const float* __restrict__ spk,
                                                  const float* __restrict__ Wspk,
                                                  const float* __restrict__ bspk,
                                                  float* __restrict__ sproj)
{
  __shared__ float red[4][64];
  int b = blockIdx.x, nb = blockIdx.y;
  int dl = threadIdx.x & 63, kc = threadIdx.x >> 6;
  int d = nb * 64 + dl;
  const float* sprow = spk + b * D_;
  float a0 = 0.f, a1 = 0.f;
  int kbeg = kc * 128;
  for (int k = kbeg; k < kbeg + 128; k += 2) {
    a0 += sprow[k]     * Wspk[(size_t)k * D_ + d];
    a1 += sprow[k + 1] * Wspk[(size_t)(k + 1) * D_ + d];
  }
  red[kc][dl] = a0 + a1;
  __syncthreads();
  if (kc == 0)
    sproj[b*D_ + d] = red[0][dl] + red[1][dl] + red[2][dl] + red[3][dl] + bspk[d];
}

// ---------------- prologue: x + PE + cond encodings -> X fp32 --------------
__global__ __launch_bounds__(256) void prologue_kernel(
    const float* __restrict__ x, const float* __restrict__ f0, const float* __restrict__ sp,
    const float* __restrict__ ap, const float* __restrict__ Wf0, const float* __restrict__ bf0,
    const float* __restrict__ Wsp, const float* __restrict__ bsp,
    const float* __restrict__ Wap, const float* __restrict__ bap,
    const float* __restrict__ sproj, float* __restrict__ X)
{
  int row = blockIdx.x, tid = threadIdx.x;
  int b = row >> 11, s = row & 2047;
  float vf0 = f0[row], vsp = sp[row], vap = ap[row];
  for (int j = 0; j < 2; ++j) {
    int d = tid + j * 256;
    int i = d >> 1;
    float div = expf((float)(2*i) * -0.01798894603f);  // -ln(10000)/512
    float arg = (float)s * div;
    float pe = (d & 1) ? cosf(arg) : sinf(arg);
    float v = x[(size_t)row*D_ + d] + pe
            + vf0*Wf0[d] + bf0[d] + vsp*Wsp[d] + bsp[d] + vap*Wap[d] + bap[d]
            + sproj[b*D_ + d];
    X[(size_t)row*D_ + d] = v;
  }
}

// ---------------- layernorm: X fp32 row -> bf16 (or fp32 final) ------------
__global__ __launch_bounds__(256) void ln_kernel(
    const float* __restrict__ X, const float* __restrict__ g, const float* __restrict__ bta,
    short* __restrict__ outB, float* __restrict__ outF, int f32out)
{
  __shared__ float red[8];
  int row = blockIdx.x, tid = threadIdx.x;
  const float* xr = X + (size_t)row * D_;
  float v0 = xr[tid], v1 = xr[tid + 256];
  float s = v0 + v1, q = v0*v0 + v1*v1;
  for (int off = 1; off < 64; off <<= 1) { s += __shfl_xor(s, off); q += __shfl_xor(q, off); }
  int w = tid >> 6;
  if ((tid & 63) == 0) { red[w*2] = s; red[w*2 + 1] = q; }
  __syncthreads();
  s = red[0] + red[2] + red[4] + red[6];
  q = red[1] + red[3] + red[5] + red[7];
  float mean = s * (1.0f / D_);
  float var = q * (1.0f / D_) - mean * mean;
  float rstd = rsqrtf(var + 1e-5f);
  float o0 = (v0 - mean) * rstd * g[tid] + bta[tid];
  float o1 = (v1 - mean) * rstd * g[tid + 256] + bta[tid + 256];
  if (f32out) {
    outF[(size_t)row*D_ + tid] = o0; outF[(size_t)row*D_ + tid + 256] = o1;
  } else {
    outB[(size_t)row*D_ + tid] = f2bf(o0); outB[(size_t)row*D_ + tid + 256] = f2bf(o1);
  }
}

// ---------------- bf16 MFMA GEMM (round-22: 128x64 tile, no atomics) -------
// Round-21 lesson: 128x128 tile REGRESSED (+30us) -- K=512 is too short
// (nkt=8) to amortize the extra per-kt LDS traffic; m97's 912TF point needs
// K=4096-scale loops. Reverted to the proven 128x64 tile.
// Round-22 change: MODE_RES drops split-K + atomicAdd. o (z=2) + ffn2 (z=4)
// issued 12.6M device-scope fp32 atomics/layer onto X -- serialized L2
// round-trips invisible in FETCH/WRITE. Now z=1: each output element owned
// by ONE thread -> plain read-modify-write X[idx] += acc (stream order
// guarantees X holds the residual). Grids: o (32,8,1) nkt=8, ffn2 (32,8,1)
// nkt=32 -- both exactly 256 blocks = 1/CU.
// Grid: x = m-block (32, 128 rows each), y = n-block (64 cols).
// gridDim.x = 32 == 0 mod 8 -> A-slice stays XCD-local (same m -> same XCD).
template<int MODE>
__device__ __forceinline__ void gemm_body(
    const short* __restrict__ A, const short* __restrict__ Wt,
    const float* __restrict__ bias, int K, int N,
    float* outF, short* outB)
{
  __shared__ short sA[2][4096];  // [panel][128 rows][32 k]
  __shared__ short sB[2][2048];  // [panel][64 rows][32 k]
  const int tid = threadIdx.x;
  const int w = tid >> 6, lane = tid & 63;
  const int col = lane & 15, quad = lane >> 4;
  const int m0 = blockIdx.x * 128, n0 = blockIdx.y * 64;
  const int nkt = K >> 6;

  const int rowT = tid >> 2, kcA = tid & 3;
  const size_t kc8 = kcA * 8;

  f4v acc[2][4] = {};
  for (int kt = 0; kt < nkt; ++kt) {
    const int k0 = kt * 64;
    __syncthreads();
    for (int p = 0; p < 2; ++p) {
      gload16(A + (size_t)(m0 + rowT) * K + k0 + p*32 + kc8,       &sA[p][(w*16) * 32]);
      gload16(A + (size_t)(m0 + 64 + rowT) * K + k0 + p*32 + kc8,  &sA[p][(64 + w*16) * 32]);
      gload16(Wt + (size_t)(n0 + rowT) * K + k0 + p*32 + kc8,      &sB[p][(w*16) * 32]);
    }
    __syncthreads();
    for (int p = 0; p < 2; ++p) {
      s8v af[2], bfr[4];
      for (int mt = 0; mt < 2; ++mt)
        af[mt] = *(const s8v*)&sA[p][(w*32 + mt*16 + col) * 32 + quad * 8];
      for (int nt = 0; nt < 4; ++nt)
        bfr[nt] = *(const s8v*)&sB[p][(nt*16 + col) * 32 + quad * 8];
      for (int mt = 0; mt < 2; ++mt)
        for (int nt = 0; nt < 4; ++nt)
          acc[mt][nt] = __builtin_amdgcn_mfma_f32_16x16x32_bf16(af[mt], bfr[nt], acc[mt][nt], 0, 0, 0);
    }
  }

  const float qsc = (MODE == MODE_BF16 && n0 < 512) ? 0.18033688f : 1.0f;  // 0.125*log2e
  float bz[4];
  for (int nt = 0; nt < 4; ++nt)
    bz[nt] = bias[n0 + nt*16 + col];
  for (int mt = 0; mt < 2; ++mt) {
    int mbase = m0 + w*32 + mt*16 + quad*4;
    for (int nt = 0; nt < 4; ++nt) {
      int n = n0 + nt*16 + col;
      for (int r = 0; r < 4; ++r) {
        float v = acc[mt][nt][r] + bz[nt];
        size_t idx = (size_t)(mbase + r) * N + n;
        if (MODE == MODE_RES) {
          outF[idx] = outF[idx] + v;   // z=1: single owner, plain RMW
        } else if (MODE == MODE_GELU) {
          outB[idx] = f2bf(0.5f * v * (1.0f + erff(v * 0.70710678118f)));
        } else {
          outB[idx] = f2bf(v * qsc);
        }
      }
    }
  }
}

__global__ __launch_bounds__(256) void gemm_qkv_kernel(
    const short* __restrict__ A, const short* __restrict__ Wt,
    const float* __restrict__ bias, float* outF, short* outB)
{ gemm_body<MODE_BF16>(A, Wt, bias, 512, 1536, outF, outB); }

__global__ __launch_bounds__(256) void gemm_o_kernel(
    const short* __restrict__ A, const short* __restrict__ Wt,
    const float* __restrict__ bias, float* outF, short* outB)
{ gemm_body<MODE_RES>(A, Wt, bias, 512, 512, outF, outB); }

__global__ __launch_bounds__(256) void gemm_ffn1_kernel(
    const short* __restrict__ A, const short* __restrict__ Wt,
    const float* __restrict__ bias, float* outF, short* outB)
{ gemm_body<MODE_GELU>(A, Wt, bias, 512, 2048, outF, outB); }

__global__ __launch_bounds__(256) void gemm_ffn2_kernel(
    const short* __restrict__ A, const short* __restrict__ Wt,
    const float* __restrict__ bias, float* outF, short* outB)
{ gemm_body<MODE_RES>(A, Wt, bias, 2048, 512, outF, outB); }

// ---------------- V transpose: QKV V-part (b,s,h,hd) -> Vt (b,h,hd,s) ------
__global__ __launch_bounds__(256) void vtrans_kernel(const short* __restrict__ QKV,
                                                     short* __restrict__ Vt)
{
  __shared__ short t[64 * 72];
  int tid = threadIdx.x;
  int s0 = blockIdx.x * 64, bh = blockIdx.y;
  int b = bh >> 3, h = bh & 7;
  for (int it = 0; it < 2; ++it) {
    int c = it * 256 + tid;
    int sR = c >> 3, hc = c & 7;
    s8v v = *(const s8v*)(QKV + (size_t)(b*S_ + s0 + sR) * 1536 + 1024 + h*64 + hc*8);
    *(s8v*)&t[sR * 72 + hc * 8] = v;
  }
  __syncthreads();
  for (int it = 0; it < 2; ++it) {
    int c = it * 256 + tid;
    int hd = c >> 3, sc = c & 7;
    s8v v;
    for (int j = 0; j < 8; ++j) v[j] = t[(sc*8 + j) * 72 + hd];
    *(s8v*)(Vt + (size_t)(bh*64 + hd) * S_ + s0 + sc*8) = v;
  }
}

// ---------------- flash attention v9 (verified round-20: 40.2us, passed) ---
// Byte-identical to the round-20 kernel. Bias per-lane from global (idx
// range [2952,7046]), direct-Q, cvt_pk P-pack; sK/sV LDS broadcast staging.
#define SM_MT(ko, mt, ST, Bb0, Bb1, Bb2, Bb3) do {                  \
    float p0 = exp2fast(ST[0] + Bb0);                               \
    float p1 = exp2fast(ST[1] + Bb1);                               \
    float p2 = exp2fast(ST[2] + Bb2);                               \
    float p3 = exp2fast(ST[3] + Bb3);                               \
    lsum += (p0 + p1) + (p2 + p3);                                  \
    int2 pk;                                                        \
    pk.x = cvt_pk_bf16(p0, p1);                                     \
    pk.y = cvt_pk_bf16(p2, p3);                                     \
    *(int2*)&sP[w*1280 + (ko)*640 + col*40 + (mt)*16 + quad*4] = pk;\
  } while (0)

#define KOBLOCK(ko, B0a,B0b,B0c,B0d, B1a,B1b,B1c,B1d) do {                         \
    f4v st0 = {}, st1 = {};                                                        \
    s8v a00 = *(const s8v*)&sK[(ko)*2560 + 0*1280 + (0*16 + col)*40 + quad*8];     \
    s8v a01 = *(const s8v*)&sK[(ko)*2560 + 1*1280 + (0*16 + col)*40 + quad*8];     \
    s8v a10 = *(const s8v*)&sK[(ko)*2560 + 0*1280 + (1*16 + col)*40 + quad*8];     \
    s8v a11 = *(const s8v*)&sK[(ko)*2560 + 1*1280 + (1*16 + col)*40 + quad*8];     \
    st0 = __builtin_amdgcn_mfma_f32_16x16x32_bf16(a00, bQ0, st0, 0, 0, 0);         \
    st0 = __builtin_amdgcn_mfma_f32_16x16x32_bf16(a01, bQ1, st0, 0, 0, 0);         \
    st1 = __builtin_amdgcn_mfma_f32_16x16x32_bf16(a10, bQ0, st1, 0, 0, 0);         \
    st1 = __builtin_amdgcn_mfma_f32_16x16x32_bf16(a11, bQ1, st1, 0, 0, 0);         \
    SM_MT(ko, 0, st0, B0a,B0b,B0c,B0d);                                            \
    SM_MT(ko, 1, st1, B1a,B1b,B1c,B1d);                                            \
    s8v aP = *(const s8v*)&sP[w*1280 + (ko)*640 + col*40 + quad*8];                \
    s8v v0 = *(const s8v*)&sV[(ko)*2560 + ( 0 + col)*40 + quad*8];                 \
    s8v v1 = *(const s8v*)&sV[(ko)*2560 + (16 + col)*40 + quad*8];                 \
    s8v v2 = *(const s8v*)&sV[(ko)*2560 + (32 + col)*40 + quad*8];                 \
    s8v v3 = *(const s8v*)&sV[(ko)*2560 + (48 + col)*40 + quad*8];                 \
    o0 = __builtin_amdgcn_mfma_f32_16x16x32_bf16(aP, v0, o0, 0, 0, 0);             \
    o1 = __builtin_amdgcn_mfma_f32_16x16x32_bf16(aP, v1, o1, 0, 0, 0);             \
    o2 = __builtin_amdgcn_mfma_f32_16x16x32_bf16(aP, v2, o2, 0, 0, 0);             \
    o3 = __builtin_amdgcn_mfma_f32_16x16x32_bf16(aP, v3, o3, 0, 0, 0);             \
  } while (0)

__global__ __launch_bounds__(512) void flash_kernel(
    const short* __restrict__ QKV, const short* __restrict__ Vt,
    const float* __restrict__ tabT, short* __restrict__ AO)
{
  __shared__ __attribute__((aligned(16))) short sK[2 * 2 * 32 * 40];  // [ko][hc][kk][40]
  __shared__ __attribute__((aligned(16))) short sV[2 * 64 * 40];      // [ko][hd][40]
  __shared__ __attribute__((aligned(16))) short sP[8 * 2 * 16 * 40];  // [w][ko][q][40]
  __shared__ float sRow[8 * 16];

  const int tid = threadIdx.x;
  const int w = tid >> 6, lane = tid & 63;
  const int col = lane & 15, quad = lane >> 4;
  const int bh = blockIdx.x, qt = blockIdx.y;
  const int b = bh >> 3, h = bh & 7;
  const int q0 = qt * 128;
  const int wq = w * 16;
  const int nkt = S_ / 64;
  const float* tabh = tabT + (size_t)h * NREL_;
  // per-lane bias base: element (kt*64 + ko*32 + mt*16 + j) relative to this
  const float* tbL = tabh + (OFF_ - q0 + quad*4 - wq - col);

  // Q fragments direct from global (one 16B load per lane per hc)
  const short* gQ = QKV + (size_t)(b*S_ + q0 + wq + col) * 1536 + h*64 + quad*8;
  s8v bQ0 = *(const s8v*)gQ;
  s8v bQ1 = *(const s8v*)(gQ + 32);

  const int c4 = tid & 3;
  const int kK = (tid >> 2) & 63, hcK = tid >> 8;
  const short* gK = QKV + (size_t)(b*S_ + kK) * 1536 + 512 + h*64 + hcK*32 + c4*8;
  short* dK = &sK[(kK >> 5)*2560 + hcK*1280 + (kK & 31)*40 + c4*8];
  const int c8 = tid & 7, hdV = tid >> 3;
  const short* gV = Vt + (size_t)(bh*64 + hdV) * S_ + c8*8;
  short* dV = &sV[(c8 >> 2)*2560 + hdV*40 + (c8 & 3)*8];

  int4 rk = *(const int4*)gK;
  int4 rv = *(const int4*)gV;

  float lsum = 0.0f;
  f4v o0 = {}, o1 = {}, o2 = {}, o3 = {};

  for (int kt = 0; kt < nkt; ++kt) {
    // bias fetch for this tile (global, L2-hot): issued before both barriers
    const float* tb = tbL + kt * 64;
    float bA0 = tb[0],  bA1 = tb[1],  bA2 = tb[2],  bA3 = tb[3];
    float bB0 = tb[16], bB1 = tb[17], bB2 = tb[18], bB3 = tb[19];
    float bC0 = tb[32], bC1 = tb[33], bC2 = tb[34], bC3 = tb[35];
    float bD0 = tb[48], bD1 = tb[49], bD2 = tb[50], bD3 = tb[51];
    __syncthreads();
    *(int4*)dK = rk;
    *(int4*)dV = rv;
    __syncthreads();
    if (kt + 1 < nkt) {
      rk = *(const int4*)(gK + (size_t)(kt + 1) * 64 * 1536);
      rv = *(const int4*)(gV + (kt + 1) * 64);
    }
    KOBLOCK(0, bA0, bA1, bA2, bA3, bB0, bB1, bB2, bB3);
    KOBLOCK(1, bC0, bC1, bC2, bC3, bD0, bD1, bD2, bD3);
  }

  lsum += __shfl_xor(lsum, 16);
  lsum += __shfl_xor(lsum, 32);
  if (lane < 16) sRow[w*16 + lane] = lsum;
  float rs0 = sRow[w*16 + quad*4 + 0];
  float rs1 = sRow[w*16 + quad*4 + 1];
  float rs2 = sRow[w*16 + quad*4 + 2];
  float rs3 = sRow[w*16 + quad*4 + 3];
  size_t mrow = (size_t)(b*S_ + q0 + wq + quad*4);
  short* aoBase = AO + mrow * 512 + h*64 + col;
  aoBase[0*512 +  0] = f2bf(o0[0] / rs0);
  aoBase[1*512 +  0] = f2bf(o0[1] / rs1);
  aoBase[2*512 +  0] = f2bf(o0[2] / rs2);
  aoBase[3*512 +  0] = f2bf(o0[3] / rs3);
  aoBase[0*512 + 16] = f2bf(o1[0] / rs0);
  aoBase[1*512 + 16] = f2bf(o1[1] / rs1);
  aoBase[2*512 + 16] = f2bf(o1[2] / rs2);
  aoBase[3*512 + 16] = f2bf(o1[3] / rs3);
  aoBase[0*512 + 32] = f2bf(o2[0] / rs0);
  aoBase[1*512 + 32] = f2bf(o2[1] / rs1);
  aoBase[2*512 + 32] = f2bf(o2[2] / rs2);
  aoBase[3*512 + 32] = f2bf(o2[3] / rs3);
  aoBase[0*512 + 48] = f2bf(o3[0] / rs0);
  aoBase[1*512 + 48] = f2bf(o3[1] / rs1);
  aoBase[2*512 + 48] = f2bf(o3[2] / rs2);
  aoBase[3*512 + 48] = f2bf(o3[3] / rs3);
}

// ===========================================================================
extern "C" void kernel_launch(void* const* d_in, const int* in_sizes, int n_in,
                              void* d_out, int out_size, void* d_ws, size_t ws_size,
                              hipStream_t stream)
{
  const float* x    = (const float*)d_in[0];
  const float* f0   = (const float*)d_in[1];
  const float* sp   = (const float*)d_in[2];
  const float* ap   = (const float*)d_in[3];
  const float* spk  = (const float*)d_in[4];
  const float* Wf0  = (const float*)d_in[5];  const float* bf0  = (const float*)d_in[6];
  const float* Wsp  = (const float*)d_in[7];  const float* bsp  = (const float*)d_in[8];
  const float* Wap  = (const float*)d_in[9];  const float* bap  = (const float*)d_in[10];
  const float* Wspk = (const float*)d_in[11]; const float* bspk = (const float*)d_in[12];
  const float* Wq   = (const float*)d_in[13]; const float* bq   = (const float*)d_in[14];
  const float* Wk   = (const float*)d_in[15]; const float* bk   = (const float*)d_in[16];
  const float* Wv   = (const float*)d_in[17]; const float* bv   = (const float*)d_in[18];
  const float* Wo   = (const float*)d_in[19]; const float* bo   = (const float*)d_in[20];
  const float* ln1g = (const float*)d_in[21]; const float* ln1b = (const float*)d_in[22];
  const float* ln2g = (const float*)d_in[23]; const float* ln2b = (const float*)d_in[24];
  const float* W1   = (const float*)d_in[25]; const float* b1   = (const float*)d_in[26];
  const float* W2   = (const float*)d_in[27]; const float* b2   = (const float*)d_in[28];
  const float* tab  = (const float*)d_in[29];
  const float* gfin = (const float*)d_in[30]; const float* bfin = (const float*)d_in[31];

  char* p = (char*)d_ws;
  auto alloc = [&](size_t bytes) { char* r = p; p += (bytes + 255) & ~(size_t)255; return r; };
  short* WqkvT = (short*)alloc((size_t)L_ * 1536 * 512 * 2);
  short* WoT   = (short*)alloc((size_t)L_ * 512 * 512 * 2);
  short* W1T   = (short*)alloc((size_t)L_ * 2048 * 512 * 2);
  short* W2T   = (short*)alloc((size_t)L_ * 512 * 2048 * 2);
  float* bqkv  = (float*)alloc((size_t)L_ * 1536 * 4);
  float* X     = (float*)alloc((size_t)M_ * D_ * 4);
  short* Hb    = (short*)alloc((size_t)M_ * D_ * 2);
  short* AO    = (short*)alloc((size_t)M_ * D_ * 2);
  short* QKVb  = (short*)alloc((size_t)M_ * 1536 * 2);
  short* VtG   = (short*)alloc((size_t)B_ * H_ * HD_ * S_ * 2);
  short* H1b   = QKVb;  // alias: FFN hidden (M,F) reuses QKVb+VtG region (exactly 16 MB)
  float* sproj = (float*)alloc((size_t)B_ * D_ * 4);
  float* tabT  = (float*)alloc((size_t)L_ * H_ * NREL_ * 4);

  dim3 b256(256);
  dim3 tb(32, 8);
  packb_kernel<<<dim3((L_*1536 + 255)/256), b256, 0, stream>>>(bq, bk, bv, bqkv);
  tabt_kernel<<<dim3((L_*H_*NREL_ + 255)/256), b256, 0, stream>>>(tab, tabT);
  transpose_kernel<<<dim3(16, 16, L_), tb, 0, stream>>>(Wq, WqkvT, 512, 512, 512*512, 1536*512, 0);
  transpose_kernel<<<dim3(16, 16, L_), tb, 0, stream>>>(Wk, WqkvT, 512, 512, 512*512, 1536*512, 512);
  transpose_kernel<<<dim3(16, 16, L_), tb, 0, stream>>>(Wv, WqkvT, 512, 512, 512*512, 1536*512, 1024);
  transpose_kernel<<<dim3(16, 16, L_), tb, 0, stream>>>(Wo, WoT, 512, 512, 512*512, 512*512, 0);
  transpose_kernel<<<dim3(64, 16, L_), tb, 0, stream>>>(W1, W1T, 512, 2048, 512*2048, 2048*512, 0);
  transpose_kernel<<<dim3(16, 64, L_), tb, 0, stream>>>(W2, W2T, 2048, 512, 2048*512, 512*2048, 0);
  spk_kernel<<<dim3(B_, 8), b256, 0, stream>>>(spk, Wspk, bspk, sproj);
  prologue_kernel<<<dim3(M_), b256, 0, stream>>>(x, f0, sp, ap, Wf0, bf0, Wsp, bsp, Wap, bap, sproj, X);

  for (int l = 0; l < L_; ++l) {
    ln_kernel<<<dim3(M_), b256, 0, stream>>>(X, ln1g + l*D_, ln1b + l*D_, Hb, nullptr, 0);
    gemm_qkv_kernel<<<dim3(32, 24, 1), b256, 0, stream>>>(
        Hb, WqkvT + (size_t)l*1536*512, bqkv + l*1536, nullptr, QKVb);
    vtrans_kernel<<<dim3(S_/64, B_*H_), b256, 0, stream>>>(QKVb, VtG);
    flash_kernel<<<dim3(B_*H_, S_/128), dim3(512), 0, stream>>>(QKVb, VtG, tabT + (size_t)l*H_*NREL_, AO);
    gemm_o_kernel<<<dim3(32, 8, 1), b256, 0, stream>>>(
        AO, WoT + (size_t)l*512*512, bo + l*D_, X, nullptr);
    ln_kernel<<<dim3(M_), b256, 0, stream>>>(X, ln2g + l*D_, ln2b + l*D_, Hb, nullptr, 0);
    gemm_ffn1_kernel<<<dim3(32, 32, 1), b256, 0, stream>>>(
        Hb, W1T + (size_t)l*2048*512, b1 + l*F_, nullptr, H1b);
    gemm_ffn2_kernel<<<dim3(32, 8, 1), b256, 0, stream>>>(
        H1b, W2T + (size_t)l*512*2048, b2 + l*D_, X, nullptr);
  }
  ln_kernel<<<dim3(M_), b256, 0, stream>>>(X, gfin, bfin, nullptr, (float*)d_out, 1);
}

// Round 13
// 911.812 us; speedup vs baseline: 1.1545x; 1.0061x over previous
//
#include <hip/hip_runtime.h>
#include <hip/hip_bf16.h>

#define B_ 2
#define S_ 2048
#define D_ 512
#define H_ 8
#define L_ 6
#define F_ 2048
#define HD_ 64
#define M_ 4096
#define OFF_ 4999
#define NREL_ 9999

typedef short s8v __attribute__((ext_vector_type(8)));
typedef float f4v __attribute__((ext_vector_type(4)));

enum { MODE_BF16 = 0, MODE_RES = 1, MODE_GELU = 2 };

__device__ __forceinline__ short f2bf(float f) {
  unsigned u = __float_as_uint(f);
  unsigned r = (u + 0x7fffu + ((u >> 16) & 1u)) >> 16;
  return (short)r;
}

__device__ __forceinline__ float exp2fast(float x) {
  float r;
  asm("v_exp_f32 %0, %1" : "=v"(r) : "v"(x));
  return r;
}

__device__ __forceinline__ int cvt_pk_bf16(float lo, float hi) {
  int r;
  asm("v_cvt_pk_bf16_f32 %0, %1, %2" : "=v"(r) : "v"(lo), "v"(hi));
  return r;
}

__device__ __forceinline__ void gload16(const void* g, const void* l) {
  __builtin_amdgcn_global_load_lds((const __attribute__((address_space(1))) unsigned int*)g,
                                   (__attribute__((address_space(3))) unsigned int*)l,
                                   16, 0, 0);
}

// ---------------- weight transpose: src fp32 (K,N) -> dst bf16 (N,K) -------
__global__ void transpose_kernel(const float* __restrict__ src, short* __restrict__ dst,
                                 int K, int N, long srcBS, long dstBS, int rowOff)
{
  __shared__ float t[32][33];
  int tx = threadIdx.x, ty = threadIdx.y;  // block (32,8)
  int n0 = blockIdx.x * 32, k0 = blockIdx.y * 32, l = blockIdx.z;
  const float* s = src + (size_t)l * srcBS;
  short* d = dst + (size_t)l * dstBS;
  for (int j = 0; j < 4; ++j)
    t[ty + j*8][tx] = s[(size_t)(k0 + ty + j*8) * N + n0 + tx];
  __syncthreads();
  for (int j = 0; j < 4; ++j)
    d[(size_t)(rowOff + n0 + ty + j*8) * K + k0 + tx] = f2bf(t[tx][ty + j*8]);
}

__global__ void packb_kernel(const float* __restrict__ bq, const float* __restrict__ bk,
                             const float* __restrict__ bv, float* __restrict__ bqkv)
{
  int i = blockIdx.x * 256 + threadIdx.x;
  if (i >= L_ * 1536) return;
  int l = i / 1536, j = i % 1536;
  float v = (j < 512) ? bq[l*512 + j] : (j < 1024) ? bk[l*512 + j - 512] : bv[l*512 + j - 1024];
  bqkv[i] = v;
}

// ---- bias table transpose + pre-scale by log2(e): exp2-domain softmax -----
__global__ void tabt_kernel(const float* __restrict__ tab, float* __restrict__ tabT)
{
  int i = blockIdx.x * 256 + threadIdx.x;
  if (i >= L_ * H_ * NREL_) return;
  int l = i / (H_ * NREL_), rem = i % (H_ * NREL_);
  int h = rem / NREL_, idx = rem % NREL_;
  tabT[i] = tab[((size_t)l * NREL_ + idx) * H_ + h] * 1.44269504f;
}

// ---------------- spk_emb @ Wspk + bspk: grid (B_, 8), k-split + LDS reduce -
__global__ __launch_bounds__(256) void spk_kernel(const float* __restrict__ spk,
                                                  const float* __restrict__ Wspk,
                                                  const float* __restrict__ bspk,
                                                  float* __restrict__ sproj)
{
  __shared__ float red[4][64];
  int b = blockIdx.x, nb = blockIdx.y;
  int dl = threadIdx.x & 63, kc = threadIdx.x >> 6;
  int d = nb * 64 + dl;
  const float* sprow = spk + b * D_;
  float a0 = 0.f, a1 = 0.f;
  int kbeg = kc * 128;
  for (int k = kbeg; k < kbeg + 128; k += 2) {
    a0 += sprow[k]     * Wspk[(size_t)k * D_ + d];
    a1 += sprow[k + 1] * Wspk[(size_t)(k + 1) * D_ + d];
  }
  red[kc][dl] = a0 + a1;
  __syncthreads();
  if (kc == 0)
    sproj[b*D_ + d] = red[0][dl] + red[1][dl] + red[2][dl] + red[3][dl] + bspk[d];
}

// ---------------- prologue: x + PE + cond encodings -> X fp32 --------------
__global__ __launch_bounds__(256) void prologue_kernel(
    const float* __restrict__ x, const float* __restrict__ f0, const float* __restrict__ sp,
    const float* __restrict__ ap, const float* __restrict__ Wf0, const float* __restrict__ bf0,
    const float* __restrict__ Wsp, const float* __restrict__ bsp,
    const float* __restrict__ Wap, const float* __restrict__ bap,
    const float* __restrict__ sproj, float* __restrict__ X)
{
  int row = blockIdx.x, tid = threadIdx.x;
  int b = row >> 11, s = row & 2047;
  float vf0 = f0[row], vsp = sp[row], vap = ap[row];
  for (int j = 0; j < 2; ++j) {
    int d = tid + j * 256;
    int i = d >> 1;
    float div = expf((float)(2*i) * -0.01798894603f);  // -ln(10000)/512
    float arg = (float)s * div;
    float pe = (d & 1) ? cosf(arg) : sinf(arg);
    float v = x[(size_t)row*D_ + d] + pe
            + vf0*Wf0[d] + bf0[d] + vsp*Wsp[d] + bsp[d] + vap*Wap[d] + bap[d]
            + sproj[b*D_ + d];
    X[(size_t)row*D_ + d] = v;
  }
}

// ---------------- layernorm: X fp32 row -> bf16 (or fp32 final) ------------
__global__ __launch_bounds__(256) void ln_kernel(
    const float* __restrict__ X, const float* __restrict__ g, const float* __restrict__ bta,
    short* __restrict__ outB, float* __restrict__ outF, int f32out)
{
  __shared__ float red[8];
  int row = blockIdx.x, tid = threadIdx.x;
  const float* xr = X + (size_t)row * D_;
  float v0 = xr[tid], v1 = xr[tid + 256];
  float s = v0 + v1, q = v0*v0 + v1*v1;
  for (int off = 1; off < 64; off <<= 1) { s += __shfl_xor(s, off); q += __shfl_xor(q, off); }
  int w = tid >> 6;
  if ((tid & 63) == 0) { red[w*2] = s; red[w*2 + 1] = q; }
  __syncthreads();
  s = red[0] + red[2] + red[4] + red[6];
  q = red[1] + red[3] + red[5] + red[7];
  float mean = s * (1.0f / D_);
  float var = q * (1.0f / D_) - mean * mean;
  float rstd = rsqrtf(var + 1e-5f);
  float o0 = (v0 - mean) * rstd * g[tid] + bta[tid];
  float o1 = (v1 - mean) * rstd * g[tid + 256] + bta[tid + 256];
  if (f32out) {
    outF[(size_t)row*D_ + tid] = o0; outF[(size_t)row*D_ + tid + 256] = o1;
  } else {
    outB[(size_t)row*D_ + tid] = f2bf(o0); outB[(size_t)row*D_ + tid + 256] = f2bf(o1);
  }
}

// ---------------- bf16 MFMA GEMM (round-22: 128x64 tile, no atomics) -------
// Round-21: 128x128 tile regressed (K=512 too short). Round-22 (verified,
// -105us): MODE_RES z=1, plain RMW X[idx]+=acc instead of atomics.
template<int MODE>
__device__ __forceinline__ void gemm_body(
    const short* __restrict__ A, const short* __restrict__ Wt,
    const float* __restrict__ bias, int K, int N,
    float* outF, short* outB)
{
  __shared__ short sA[2][4096];  // [panel][128 rows][32 k]
  __shared__ short sB[2][2048];  // [panel][64 rows][32 k]
  const int tid = threadIdx.x;
  const int w = tid >> 6, lane = tid & 63;
  const int col = lane & 15, quad = lane >> 4;
  const int m0 = blockIdx.x * 128, n0 = blockIdx.y * 64;
  const int nkt = K >> 6;

  const int rowT = tid >> 2, kcA = tid & 3;
  const size_t kc8 = kcA * 8;

  f4v acc[2][4] = {};
  for (int kt = 0; kt < nkt; ++kt) {
    const int k0 = kt * 64;
    __syncthreads();
    for (int p = 0; p < 2; ++p) {
      gload16(A + (size_t)(m0 + rowT) * K + k0 + p*32 + kc8,       &sA[p][(w*16) * 32]);
      gload16(A + (size_t)(m0 + 64 + rowT) * K + k0 + p*32 + kc8,  &sA[p][(64 + w*16) * 32]);
      gload16(Wt + (size_t)(n0 + rowT) * K + k0 + p*32 + kc8,      &sB[p][(w*16) * 32]);
    }
    __syncthreads();
    for (int p = 0; p < 2; ++p) {
      s8v af[2], bfr[4];
      for (int mt = 0; mt < 2; ++mt)
        af[mt] = *(const s8v*)&sA[p][(w*32 + mt*16 + col) * 32 + quad * 8];
      for (int nt = 0; nt < 4; ++nt)
        bfr[nt] = *(const s8v*)&sB[p][(nt*16 + col) * 32 + quad * 8];
      for (int mt = 0; mt < 2; ++mt)
        for (int nt = 0; nt < 4; ++nt)
          acc[mt][nt] = __builtin_amdgcn_mfma_f32_16x16x32_bf16(af[mt], bfr[nt], acc[mt][nt], 0, 0, 0);
    }
  }

  const float qsc = (MODE == MODE_BF16 && n0 < 512) ? 0.18033688f : 1.0f;  // 0.125*log2e
  float bz[4];
  for (int nt = 0; nt < 4; ++nt)
    bz[nt] = bias[n0 + nt*16 + col];
  for (int mt = 0; mt < 2; ++mt) {
    int mbase = m0 + w*32 + mt*16 + quad*4;
    for (int nt = 0; nt < 4; ++nt) {
      int n = n0 + nt*16 + col;
      for (int r = 0; r < 4; ++r) {
        float v = acc[mt][nt][r] + bz[nt];
        size_t idx = (size_t)(mbase + r) * N + n;
        if (MODE == MODE_RES) {
          outF[idx] = outF[idx] + v;   // z=1: single owner, plain RMW
        } else if (MODE == MODE_GELU) {
          outB[idx] = f2bf(0.5f * v * (1.0f + erff(v * 0.70710678118f)));
        } else {
          outB[idx] = f2bf(v * qsc);
        }
      }
    }
  }
}

__global__ __launch_bounds__(256) void gemm_qkv_kernel(
    const short* __restrict__ A, const short* __restrict__ Wt,
    const float* __restrict__ bias, float* outF, short* outB)
{ gemm_body<MODE_BF16>(A, Wt, bias, 512, 1536, outF, outB); }

__global__ __launch_bounds__(256) void gemm_o_kernel(
    const short* __restrict__ A, const short* __restrict__ Wt,
    const float* __restrict__ bias, float* outF, short* outB)
{ gemm_body<MODE_RES>(A, Wt, bias, 512, 512, outF, outB); }

__global__ __launch_bounds__(256) void gemm_ffn1_kernel(
    const short* __restrict__ A, const short* __restrict__ Wt,
    const float* __restrict__ bias, float* outF, short* outB)
{ gemm_body<MODE_GELU>(A, Wt, bias, 512, 2048, outF, outB); }

__global__ __launch_bounds__(256) void gemm_ffn2_kernel(
    const short* __restrict__ A, const short* __restrict__ Wt,
    const float* __restrict__ bias, float* outF, short* outB)
{ gemm_body<MODE_RES>(A, Wt, bias, 2048, 512, outF, outB); }

// ---------------- V transpose: QKV V-part (b,s,h,hd) -> Vt (b,h,hd,s) ------
__global__ __launch_bounds__(256) void vtrans_kernel(const short* __restrict__ QKV,
                                                     short* __restrict__ Vt)
{
  __shared__ short t[64 * 72];
  int tid = threadIdx.x;
  int s0 = blockIdx.x * 64, bh = blockIdx.y;
  int b = bh >> 3, h = bh & 7;
  for (int it = 0; it < 2; ++it) {
    int c = it * 256 + tid;
    int sR = c >> 3, hc = c & 7;
    s8v v = *(const s8v*)(QKV + (size_t)(b*S_ + s0 + sR) * 1536 + 1024 + h*64 + hc*8);
    *(s8v*)&t[sR * 72 + hc * 8] = v;
  }
  __syncthreads();
  for (int it = 0; it < 2; ++it) {
    int c = it * 256 + tid;
    int hd = c >> 3, sc = c & 7;
    s8v v;
    for (int j = 0; j < 8; ++j) v[j] = t[(sc*8 + j) * 72 + hd];
    *(s8v*)(Vt + (size_t)(bh*64 + hd) * S_ + s0 + sc*8) = v;
  }
}

// ---------------- flash attention v10 (round-23: wave-team K-split) --------
// v9 model (calibrated at 40.2us): per-CU/kt ~1408cy LDS data + ~830cy
// conflicts = 74% of the 3000cy step; dominated by aK (64KB) + sV (64KB)
// reads -- all 8 waves redundantly reading the same fragments. v10 re-maps
// waves from (8 qg x 64k) to (4 qg of 32 rows) x (2 k-teams of 32): each
// wave reads only its team's sK/sV half (4+4 vs 8+8 b128), computing
// partial PV over its k-half. Fragment traffic 176->112KB/kt; 8 waves kept.
// One-time end combine of o/lsum partials across teams via reused LDS.
// Bias: (mtK,qg2)=(0,0)&(1,1) share k-q -> only 12 loads/wave/kt; range
// [2952,7046] unchanged.
#define SM2(ST, Ba, Bb, Bc, Bd, LS, slotQ, kpos) do {               \
    float p0 = exp2fast(ST[0] + Ba);                                \
    float p1 = exp2fast(ST[1] + Bb);                                \
    float p2 = exp2fast(ST[2] + Bc);                                \
    float p3 = exp2fast(ST[3] + Bd);                                \
    LS += (p0 + p1) + (p2 + p3);                                    \
    int2 pk;                                                        \
    pk.x = cvt_pk_bf16(p0, p1);                                     \
    pk.y = cvt_pk_bf16(p2, p3);                                     \
    *(int2*)&sAll[10240 + w*1280 + (slotQ)*640 + col*40 + (kpos) + quad*4] = pk; \
  } while (0)

#define MFMA16(A, Bv, C) C = __builtin_amdgcn_mfma_f32_16x16x32_bf16(A, Bv, C, 0, 0, 0)

__global__ __launch_bounds__(512) void flash_kernel(
    const short* __restrict__ QKV, const short* __restrict__ Vt,
    const float* __restrict__ tabT, short* __restrict__ AO)
{
  // sK: [0,5120) shorts = [ko2][hc2][kk32][40]; sV: [5120,10240) = [ko2][hd64][40];
  // sP: [10240,20480) = [w8][qg2'][q16][40]. sComb reuses [0,16384) as f4v after loop.
  __shared__ __attribute__((aligned(16))) short sAll[20480];
  __shared__ float sRowA[256];   // [team2][qg4][qg2'2][16]

  const int tid = threadIdx.x;
  const int w = tid >> 6, lane = tid & 63;
  const int col = lane & 15, quad = lane >> 4;
  const int team = w >> 2, qg = w & 3;
  const int qbase = qg * 32;
  const int bh = blockIdx.x, qt = blockIdx.y;
  const int b = bh >> 3, h = bh & 7;
  const int q0 = qt * 128;
  const int nkt = S_ / 64;
  const float* tabh = tabT + (size_t)h * NREL_;
  // bias idx for (kt,mtK,qg2,r): tbB + kt*64 + mtK*16 - qg2*16 + r
  const float* tbB = tabh + (OFF_ - q0 - qbase - col + team*32 + quad*4);

  // Q fragments: 32 q-rows per wave (qg2 in {0,1}), direct from global
  const short* gQ0 = QKV + (size_t)(b*S_ + q0 + qbase + col) * 1536 + h*64 + quad*8;
  s8v bQ00 = *(const s8v*)gQ0;
  s8v bQ01 = *(const s8v*)(gQ0 + 32);
  const short* gQ1 = gQ0 + 16*1536;
  s8v bQ10 = *(const s8v*)gQ1;
  s8v bQ11 = *(const s8v*)(gQ1 + 32);

  // K staging (512 threads, unchanged mapping)
  const int c4 = tid & 3;
  const int kK = (tid >> 2) & 63, hcK = tid >> 8;
  const short* gK = QKV + (size_t)(b*S_ + kK) * 1536 + 512 + h*64 + hcK*32 + c4*8;
  short* dK = &sAll[(kK >> 5)*2560 + hcK*1280 + (kK & 31)*40 + c4*8];
  const int c8 = tid & 7, hdV = tid >> 3;
  const short* gV = Vt + (size_t)(bh*64 + hdV) * S_ + c8*8;
  short* dV = &sAll[5120 + (c8 >> 2)*2560 + hdV*40 + (c8 & 3)*8];

  int4 rk = *(const int4*)gK;
  int4 rv = *(const int4*)gV;

  float lsum0 = 0.0f, lsum1 = 0.0f;
  f4v o00 = {}, o01 = {}, o02 = {}, o03 = {};
  f4v o10 = {}, o11 = {}, o12 = {}, o13 = {};

  const int kofs = team * 2560;
  const int vofs = 5120 + team * 2560;

  for (int kt = 0; kt < nkt; ++kt) {
    const float* tb = tbB + kt * 64;
    float bm0 = tb[-16], bm1 = tb[-15], bm2 = tb[-14], bm3 = tb[-13];
    float b00 = tb[0],   b01 = tb[1],   b02 = tb[2],   b03 = tb[3];
    float bp0 = tb[16],  bp1 = tb[17],  bp2 = tb[18],  bp3 = tb[19];
    __syncthreads();
    *(int4*)dK = rk;
    *(int4*)dV = rv;
    __syncthreads();
    if (kt + 1 < nkt) {
      rk = *(const int4*)(gK + (size_t)(kt + 1) * 64 * 1536);
      rv = *(const int4*)(gV + (kt + 1) * 64);
    }
    // team-local K fragments (k rows team*32 + mtK*16 + col)
    s8v ak00 = *(const s8v*)&sAll[kofs + 0*1280 + ( 0 + col)*40 + quad*8];
    s8v ak01 = *(const s8v*)&sAll[kofs + 1*1280 + ( 0 + col)*40 + quad*8];
    s8v ak10 = *(const s8v*)&sAll[kofs + 0*1280 + (16 + col)*40 + quad*8];
    s8v ak11 = *(const s8v*)&sAll[kofs + 1*1280 + (16 + col)*40 + quad*8];
    f4v st00 = {}, st01 = {}, st10 = {}, st11 = {};
    MFMA16(ak00, bQ00, st00); MFMA16(ak01, bQ01, st00);   // mtK0, qg2=0
    MFMA16(ak00, bQ10, st01); MFMA16(ak01, bQ11, st01);   // mtK0, qg2=1
    MFMA16(ak10, bQ00, st10); MFMA16(ak11, bQ01, st10);   // mtK1, qg2=0
    MFMA16(ak10, bQ10, st11); MFMA16(ak11, bQ11, st11);   // mtK1, qg2=1
    SM2(st00, b00, b01, b02, b03, lsum0, 0, 0);
    SM2(st01, bm0, bm1, bm2, bm3, lsum1, 1, 0);
    SM2(st10, bp0, bp1, bp2, bp3, lsum0, 0, 16);
    SM2(st11, b00, b01, b02, b03, lsum1, 1, 16);
    s8v aP0 = *(const s8v*)&sAll[10240 + w*1280 +   0 + col*40 + quad*8];
    s8v aP1 = *(const s8v*)&sAll[10240 + w*1280 + 640 + col*40 + quad*8];
    s8v bv0 = *(const s8v*)&sAll[vofs + ( 0 + col)*40 + quad*8];
    s8v bv1 = *(const s8v*)&sAll[vofs + (16 + col)*40 + quad*8];
    s8v bv2 = *(const s8v*)&sAll[vofs + (32 + col)*40 + quad*8];
    s8v bv3 = *(const s8v*)&sAll[vofs + (48 + col)*40 + quad*8];
    MFMA16(aP0, bv0, o00); MFMA16(aP0, bv1, o01);
    MFMA16(aP0, bv2, o02); MFMA16(aP0, bv3, o03);
    MFMA16(aP1, bv0, o10); MFMA16(aP1, bv1, o11);
    MFMA16(aP1, bv2, o12); MFMA16(aP1, bv3, o13);
  }

  // ---- cross-team combine ----
  lsum0 += __shfl_xor(lsum0, 16); lsum0 += __shfl_xor(lsum0, 32);
  lsum1 += __shfl_xor(lsum1, 16); lsum1 += __shfl_xor(lsum1, 32);
  __syncthreads();   // all waves done with sK/sV/sP -> safe to reuse as sComb
  if (lane < 16) {
    sRowA[team*128 + qg*32 + lane]      = lsum0;
    sRowA[team*128 + qg*32 + 16 + lane] = lsum1;
  }
  f4v* sComb = (f4v*)sAll;
  if (team == 1) {
    sComb[(qg*8 + 0)*64 + lane] = o00;
    sComb[(qg*8 + 1)*64 + lane] = o01;
    sComb[(qg*8 + 2)*64 + lane] = o02;
    sComb[(qg*8 + 3)*64 + lane] = o03;
    sComb[(qg*8 + 4)*64 + lane] = o10;
    sComb[(qg*8 + 5)*64 + lane] = o11;
    sComb[(qg*8 + 6)*64 + lane] = o12;
    sComb[(qg*8 + 7)*64 + lane] = o13;
  }
  __syncthreads();
  if (team == 0) {
    int rbase = qg*32 + quad*4;
    float ra0 = sRowA[rbase+0] + sRowA[128+rbase+0];
    float ra1 = sRowA[rbase+1] + sRowA[128+rbase+1];
    float ra2 = sRowA[rbase+2] + sRowA[128+rbase+2];
    float ra3 = sRowA[rbase+3] + sRowA[128+rbase+3];
    float rb0 = sRowA[rbase+16+0] + sRowA[128+rbase+16+0];
    float rb1 = sRowA[rbase+16+1] + sRowA[128+rbase+16+1];
    float rb2 = sRowA[rbase+16+2] + sRowA[128+rbase+16+2];
    float rb3 = sRowA[rbase+16+3] + sRowA[128+rbase+16+3];
    short* aoRow = AO + (size_t)(b*S_ + q0 + qbase)*512 + h*64 + col;
#define WOUT(OV, qg2, nt, RA0, RA1, RA2, RA3) do {                       \
      f4v pp = OV + sComb[(qg*8 + (qg2)*4 + (nt))*64 + lane];            \
      aoRow[((qg2)*16 + quad*4 + 0)*512 + (nt)*16] = f2bf(pp[0] / RA0);  \
      aoRow[((qg2)*16 + quad*4 + 1)*512 + (nt)*16] = f2bf(pp[1] / RA1);  \
      aoRow[((qg2)*16 + quad*4 + 2)*512 + (nt)*16] = f2bf(pp[2] / RA2);  \
      aoRow[((qg2)*16 + quad*4 + 3)*512 + (nt)*16] = f2bf(pp[3] / RA3);  \
    } while (0)
    WOUT(o00, 0, 0, ra0, ra1, ra2, ra3);
    WOUT(o01, 0, 1, ra0, ra1, ra2, ra3);
    WOUT(o02, 0, 2, ra0, ra1, ra2, ra3);
    WOUT(o03, 0, 3, ra0, ra1, ra2, ra3);
    WOUT(o10, 1, 0, rb0, rb1, rb2, rb3);
    WOUT(o11, 1, 1, rb0, rb1, rb2, rb3);
    WOUT(o12, 1, 2, rb0, rb1, rb2, rb3);
    WOUT(o13, 1, 3, rb0, rb1, rb2, rb3);
#undef WOUT
  }
}

// ===========================================================================
extern "C" void kernel_launch(void* const* d_in, const int* in_sizes, int n_in,
                              void* d_out, int out_size, void* d_ws, size_t ws_size,
                              hipStream_t stream)
{
  const float* x    = (const float*)d_in[0];
  const float* f0   = (const float*)d_in[1];
  const float* sp   = (const float*)d_in[2];
  const float* ap   = (const float*)d_in[3];
  const float* spk  = (const float*)d_in[4];
  const float* Wf0  = (const float*)d_in[5];  const float* bf0  = (const float*)d_in[6];
  const float* Wsp  = (const float*)d_in[7];  const float* bsp  = (const float*)d_in[8];
  const float* Wap  = (const float*)d_in[9];  const float* bap  = (const float*)d_in[10];
  const float* Wspk = (const float*)d_in[11]; const float* bspk = (const float*)d_in[12];
  const float* Wq   = (const float*)d_in[13]; const float* bq   = (const float*)d_in[14];
  const float* Wk   = (const float*)d_in[15]; const float* bk   = (const float*)d_in[16];
  const float* Wv   = (const float*)d_in[17]; const float* bv   = (const float*)d_in[18];
  const float* Wo   = (const float*)d_in[19]; const float* bo   = (const float*)d_in[20];
  const float* ln1g = (const float*)d_in[21]; const float* ln1b = (const float*)d_in[22];
  const float* ln2g = (const float*)d_in[23]; const float* ln2b = (const float*)d_in[24];
  const float* W1   = (const float*)d_in[25]; const float* b1   = (const float*)d_in[26];
  const float* W2   = (const float*)d_in[27]; const float* b2   = (const float*)d_in[28];
  const float* tab  = (const float*)d_in[29];
  const float* gfin = (const float*)d_in[30]; const float* bfin = (const float*)d_in[31];

  char* p = (char*)d_ws;
  auto alloc = [&](size_t bytes) { char* r = p; p += (bytes + 255) & ~(size_t)255; return r; };
  short* WqkvT = (short*)alloc((size_t)L_ * 1536 * 512 * 2);
  short* WoT   = (short*)alloc((size_t)L_ * 512 * 512 * 2);
  short* W1T   = (short*)alloc((size_t)L_ * 2048 * 512 * 2);
  short* W2T   = (short*)alloc((size_t)L_ * 512 * 2048 * 2);
  float* bqkv  = (float*)alloc((size_t)L_ * 1536 * 4);
  float* X     = (float*)alloc((size_t)M_ * D_ * 4);
  short* Hb    = (short*)alloc((size_t)M_ * D_ * 2);
  short* AO    = (short*)alloc((size_t)M_ * D_ * 2);
  short* QKVb  = (short*)alloc((size_t)M_ * 1536 * 2);
  short* VtG   = (short*)alloc((size_t)B_ * H_ * HD_ * S_ * 2);
  short* H1b   = QKVb;  // alias: FFN hidden (M,F) reuses QKVb+VtG region (exactly 16 MB)
  float* sproj = (float*)alloc((size_t)B_ * D_ * 4);
  float* tabT  = (float*)alloc((size_t)L_ * H_ * NREL_ * 4);

  dim3 b256(256);
  dim3 tb(32, 8);
  packb_kernel<<<dim3((L_*1536 + 255)/256), b256, 0, stream>>>(bq, bk, bv, bqkv);
  tabt_kernel<<<dim3((L_*H_*NREL_ + 255)/256), b256, 0, stream>>>(tab, tabT);
  transpose_kernel<<<dim3(16, 16, L_), tb, 0, stream>>>(Wq, WqkvT, 512, 512, 512*512, 1536*512, 0);
  transpose_kernel<<<dim3(16, 16, L_), tb, 0, stream>>>(Wk, WqkvT, 512, 512, 512*512, 1536*512, 512);
  transpose_kernel<<<dim3(16, 16, L_), tb, 0, stream>>>(Wv, WqkvT, 512, 512, 512*512, 1536*512, 1024);
  transpose_kernel<<<dim3(16, 16, L_), tb, 0, stream>>>(Wo, WoT, 512, 512, 512*512, 512*512, 0);
  transpose_kernel<<<dim3(64, 16, L_), tb, 0, stream>>>(W1, W1T, 512, 2048, 512*2048, 2048*512, 0);
  transpose_kernel<<<dim3(16, 64, L_), tb, 0, stream>>>(W2, W2T, 2048, 512, 2048*512, 512*2048, 0);
  spk_kernel<<<dim3(B_, 8), b256, 0, stream>>>(spk, Wspk, bspk, sproj);
  prologue_kernel<<<dim3(M_), b256, 0, stream>>>(x, f0, sp, ap, Wf0, bf0, Wsp, bsp, Wap, bap, sproj, X);

  for (int l = 0; l < L_; ++l) {
    ln_kernel<<<dim3(M_), b256, 0, stream>>>(X, ln1g + l*D_, ln1b + l*D_, Hb, nullptr, 0);
    gemm_qkv_kernel<<<dim3(32, 24, 1), b256, 0, stream>>>(
        Hb, WqkvT + (size_t)l*1536*512, bqkv + l*1536, nullptr, QKVb);
    vtrans_kernel<<<dim3(S_/64, B_*H_), b256, 0, stream>>>(QKVb, VtG);
    flash_kernel<<<dim3(B_*H_, S_/128), dim3(512), 0, stream>>>(QKVb, VtG, tabT + (size_t)l*H_*NREL_, AO);
    gemm_o_kernel<<<dim3(32, 8, 1), b256, 0, stream>>>(
        AO, WoT + (size_t)l*512*512, bo + l*D_, X, nullptr);
    ln_kernel<<<dim3(M_), b256, 0, stream>>>(X, ln2g + l*D_, ln2b + l*D_, Hb, nullptr, 0);
    gemm_ffn1_kernel<<<dim3(32, 32, 1), b256, 0, stream>>>(
        Hb, W1T + (size_t)l*2048*512, b1 + l*F_, nullptr, H1b);
    gemm_ffn2_kernel<<<dim3(32, 8, 1), b256, 0, stream>>>(
        H1b, W2T + (size_t)l*512*2048, b2 + l*D_, X, nullptr);
  }
  ln_kernel<<<dim3(M_), b256, 0, stream>>>(X, gfin, bfin, nullptr, (float*)d_out, 1);
}

// Round 14
// 872.110 us; speedup vs baseline: 1.2071x; 1.0455x over previous
//
#include <hip/hip_runtime.h>
#include <hip/hip_bf16.h>

#define B_ 2
#define S_ 2048
#define D_ 512
#define H_ 8
#define L_ 6
#define F_ 2048
#define HD_ 64
#define M_ 4096
#define OFF_ 4999
#define NREL_ 9999

typedef short s8v __attribute__((ext_vector_type(8)));
typedef float f4v __attribute__((ext_vector_type(4)));

enum { MODE_BF16 = 0, MODE_RES = 1, MODE_GELU = 2 };

__device__ __forceinline__ short f2bf(float f) {
  unsigned u = __float_as_uint(f);
  unsigned r = (u + 0x7fffu + ((u >> 16) & 1u)) >> 16;
  return (short)r;
}

__device__ __forceinline__ float exp2fast(float x) {
  float r;
  asm("v_exp_f32 %0, %1" : "=v"(r) : "v"(x));
  return r;
}

__device__ __forceinline__ int cvt_pk_bf16(float lo, float hi) {
  int r;
  asm("v_cvt_pk_bf16_f32 %0, %1, %2" : "=v"(r) : "v"(lo), "v"(hi));
  return r;
}

__device__ __forceinline__ void gload16(const void* g, const void* l) {
  __builtin_amdgcn_global_load_lds((const __attribute__((address_space(1))) unsigned int*)g,
                                   (__attribute__((address_space(3))) unsigned int*)l,
                                   16, 0, 0);
}

// ---------------- weight transpose: src fp32 (K,N) -> dst bf16 (N,K) -------
__global__ void transpose_kernel(const float* __restrict__ src, short* __restrict__ dst,
                                 int K, int N, long srcBS, long dstBS, int rowOff)
{
  __shared__ float t[32][33];
  int tx = threadIdx.x, ty = threadIdx.y;  // block (32,8)
  int n0 = blockIdx.x * 32, k0 = blockIdx.y * 32, l = blockIdx.z;
  const float* s = src + (size_t)l * srcBS;
  short* d = dst + (size_t)l * dstBS;
  for (int j = 0; j < 4; ++j)
    t[ty + j*8][tx] = s[(size_t)(k0 + ty + j*8) * N + n0 + tx];
  __syncthreads();
  for (int j = 0; j < 4; ++j)
    d[(size_t)(rowOff + n0 + ty + j*8) * K + k0 + tx] = f2bf(t[tx][ty + j*8]);
}

__global__ void packb_kernel(const float* __restrict__ bq, const float* __restrict__ bk,
                             const float* __restrict__ bv, float* __restrict__ bqkv)
{
  int i = blockIdx.x * 256 + threadIdx.x;
  if (i >= L_ * 1536) return;
  int l = i / 1536, j = i % 1536;
  float v = (j < 512) ? bq[l*512 + j] : (j < 1024) ? bk[l*512 + j - 512] : bv[l*512 + j - 1024];
  bqkv[i] = v;
}

// ---- bias table transpose + pre-scale by log2(e): exp2-domain softmax -----
__global__ void tabt_kernel(const float* __restrict__ tab, float* __restrict__ tabT)
{
  int i = blockIdx.x * 256 + threadIdx.x;
  if (i >= L_ * H_ * NREL_) return;
  int l = i / (H_ * NREL_), rem = i % (H_ * NREL_);
  int h = rem / NREL_, idx = rem % NREL_;
  tabT[i] = tab[((size_t)l * NREL_ + idx) * H_ + h] * 1.44269504f;
}

// ---------------- spk_emb @ Wspk + bspk: grid (B_, 8), k-split + LDS reduce -
__global__ __launch_bounds__(256) void spk_kernel(const float* __restrict__ spk,
                                                  const float* __restrict__ Wspk,
                                                  const float* __restrict__ bspk,
                                                  float* __restrict__ sproj)
{
  __shared__ float red[4][64];
  int b = blockIdx.x, nb = blockIdx.y;
  int dl = threadIdx.x & 63, kc = threadIdx.x >> 6;
  int d = nb * 64 + dl;
  const float* sprow = spk + b * D_;
  float a0 = 0.f, a1 = 0.f;
  int kbeg = kc * 128;
  for (int k = kbeg; k < kbeg + 128; k += 2) {
    a0 += sprow[k]     * Wspk[(size_t)k * D_ + d];
    a1 += sprow[k + 1] * Wspk[(size_t)(k + 1) * D_ + d];
  }
  red[kc][dl] = a0 + a1;
  __syncthreads();
  if (kc == 0)
    sproj[b*D_ + d] = red[0][dl] + red[1][dl] + red[2][dl] + red[3][dl] + bspk[d];
}

// ---------------- prologue: x + PE + cond encodings -> X fp32 --------------
__global__ __launch_bounds__(256) void prologue_kernel(
    const float* __restrict__ x, const float* __restrict__ f0, const float* __restrict__ sp,
    const float* __restrict__ ap, const float* __restrict__ Wf0, const float* __restrict__ bf0,
    const float* __restrict__ Wsp, const float* __restrict__ bsp,
    const float* __restrict__ Wap, const float* __restrict__ bap,
    const float* __restrict__ sproj, float* __restrict__ X)
{
  int row = blockIdx.x, tid = threadIdx.x;
  int b = row >> 11, s = row & 2047;
  float vf0 = f0[row], vsp = sp[row], vap = ap[row];
  for (int j = 0; j < 2; ++j) {
    int d = tid + j * 256;
    int i = d >> 1;
    float div = expf((float)(2*i) * -0.01798894603f);  // -ln(10000)/512
    float arg = (float)s * div;
    float pe = (d & 1) ? cosf(arg) : sinf(arg);
    float v = x[(size_t)row*D_ + d] + pe
            + vf0*Wf0[d] + bf0[d] + vsp*Wsp[d] + bsp[d] + vap*Wap[d] + bap[d]
            + sproj[b*D_ + d];
    X[(size_t)row*D_ + d] = v;
  }
}

// ---------------- layernorm: X fp32 row -> bf16 (or fp32 final) ------------
__global__ __launch_bounds__(256) void ln_kernel(
    const float* __restrict__ X, const float* __restrict__ g, const float* __restrict__ bta,
    short* __restrict__ outB, float* __restrict__ outF, int f32out)
{
  __shared__ float red[8];
  int row = blockIdx.x, tid = threadIdx.x;
  const float* xr = X + (size_t)row * D_;
  float v0 = xr[tid], v1 = xr[tid + 256];
  float s = v0 + v1, q = v0*v0 + v1*v1;
  for (int off = 1; off < 64; off <<= 1) { s += __shfl_xor(s, off); q += __shfl_xor(q, off); }
  int w = tid >> 6;
  if ((tid & 63) == 0) { red[w*2] = s; red[w*2 + 1] = q; }
  __syncthreads();
  s = red[0] + red[2] + red[4] + red[6];
  q = red[1] + red[3] + red[5] + red[7];
  float mean = s * (1.0f / D_);
  float var = q * (1.0f / D_) - mean * mean;
  float rstd = rsqrtf(var + 1e-5f);
  float o0 = (v0 - mean) * rstd * g[tid] + bta[tid];
  float o1 = (v1 - mean) * rstd * g[tid + 256] + bta[tid + 256];
  if (f32out) {
    outF[(size_t)row*D_ + tid] = o0; outF[(size_t)row*D_ + tid + 256] = o1;
  } else {
    outB[(size_t)row*D_ + tid] = f2bf(o0); outB[(size_t)row*D_ + tid + 256] = f2bf(o1);
  }
}

// ---------------- bf16 MFMA GEMM 128x64 (qkv/ffn1: 3-4 blocks/CU) ----------
// Round-22 (verified, -105us): MODE_RES z=1, plain RMW X[idx]+=acc.
template<int MODE>
__device__ __forceinline__ void gemm_body(
    const short* __restrict__ A, const short* __restrict__ Wt,
    const float* __restrict__ bias, int K, int N,
    float* outF, short* outB)
{
  __shared__ short sA[2][4096];  // [panel][128 rows][32 k]
  __shared__ short sB[2][2048];  // [panel][64 rows][32 k]
  const int tid = threadIdx.x;
  const int w = tid >> 6, lane = tid & 63;
  const int col = lane & 15, quad = lane >> 4;
  const int m0 = blockIdx.x * 128, n0 = blockIdx.y * 64;
  const int nkt = K >> 6;

  const int rowT = tid >> 2, kcA = tid & 3;
  const size_t kc8 = kcA * 8;

  f4v acc[2][4] = {};
  for (int kt = 0; kt < nkt; ++kt) {
    const int k0 = kt * 64;
    __syncthreads();
    for (int p = 0; p < 2; ++p) {
      gload16(A + (size_t)(m0 + rowT) * K + k0 + p*32 + kc8,       &sA[p][(w*16) * 32]);
      gload16(A + (size_t)(m0 + 64 + rowT) * K + k0 + p*32 + kc8,  &sA[p][(64 + w*16) * 32]);
      gload16(Wt + (size_t)(n0 + rowT) * K + k0 + p*32 + kc8,      &sB[p][(w*16) * 32]);
    }
    __syncthreads();
    for (int p = 0; p < 2; ++p) {
      s8v af[2], bfr[4];
      for (int mt = 0; mt < 2; ++mt)
        af[mt] = *(const s8v*)&sA[p][(w*32 + mt*16 + col) * 32 + quad * 8];
      for (int nt = 0; nt < 4; ++nt)
        bfr[nt] = *(const s8v*)&sB[p][(nt*16 + col) * 32 + quad * 8];
      for (int mt = 0; mt < 2; ++mt)
        for (int nt = 0; nt < 4; ++nt)
          acc[mt][nt] = __builtin_amdgcn_mfma_f32_16x16x32_bf16(af[mt], bfr[nt], acc[mt][nt], 0, 0, 0);
    }
  }

  const float qsc = (MODE == MODE_BF16 && n0 < 512) ? 0.18033688f : 1.0f;  // 0.125*log2e
  float bz[4];
  for (int nt = 0; nt < 4; ++nt)
    bz[nt] = bias[n0 + nt*16 + col];
  for (int mt = 0; mt < 2; ++mt) {
    int mbase = m0 + w*32 + mt*16 + quad*4;
    for (int nt = 0; nt < 4; ++nt) {
      int n = n0 + nt*16 + col;
      for (int r = 0; r < 4; ++r) {
        float v = acc[mt][nt][r] + bz[nt];
        size_t idx = (size_t)(mbase + r) * N + n;
        if (MODE == MODE_RES) {
          outF[idx] = outF[idx] + v;
        } else if (MODE == MODE_GELU) {
          outB[idx] = f2bf(0.5f * v * (1.0f + erff(v * 0.70710678118f)));
        } else {
          outB[idx] = f2bf(v * qsc);
        }
      }
    }
  }
}

// ---------------- bf16 MFMA GEMM 64x64 (o/ffn2, round-24) ------------------
// Round-23 analysis: o/ffn2 at 256 blocks = 1 block/CU, 4 waves, 2-barrier
// K-loop -> every kt's HBM/L2 load latency (~600-900cy) fully exposed (all
// resident waves wait at the same barrier); ffn2 serializes this x32.
// 64x64 tile -> grid (64, N/64) = 512 blocks = 2/CU: second resident block
// hides the other's barrier drain. B-traffic doubles but B = L2-resident
// weight (<=2MB); A-traffic unchanged. z=1 RMW epilogue kept (no atomics).
template<int MODE>
__device__ __forceinline__ void gemm_body64(
    const short* __restrict__ A, const short* __restrict__ Wt,
    const float* __restrict__ bias, int K, int N,
    float* outF, short* outB)
{
  __shared__ short sA[2][2048];  // [panel][64 rows][32 k]
  __shared__ short sB[2][2048];  // [panel][64 rows][32 k]
  const int tid = threadIdx.x;
  const int w = tid >> 6, lane = tid & 63;
  const int col = lane & 15, quad = lane >> 4;
  const int m0 = blockIdx.x * 64, n0 = blockIdx.y * 64;
  const int nkt = K >> 6;

  const int rowT = tid >> 2, kcA = tid & 3;
  const size_t kc8 = kcA * 8;

  f4v acc[4] = {};
  for (int kt = 0; kt < nkt; ++kt) {
    const int k0 = kt * 64;
    __syncthreads();
    for (int p = 0; p < 2; ++p) {
      gload16(A + (size_t)(m0 + rowT) * K + k0 + p*32 + kc8,   &sA[p][(w*16) * 32]);
      gload16(Wt + (size_t)(n0 + rowT) * K + k0 + p*32 + kc8,  &sB[p][(w*16) * 32]);
    }
    __syncthreads();
    for (int p = 0; p < 2; ++p) {
      s8v af = *(const s8v*)&sA[p][(w*16 + col) * 32 + quad * 8];
      s8v b0 = *(const s8v*)&sB[p][( 0 + col) * 32 + quad * 8];
      s8v b1 = *(const s8v*)&sB[p][(16 + col) * 32 + quad * 8];
      s8v b2 = *(const s8v*)&sB[p][(32 + col) * 32 + quad * 8];
      s8v b3 = *(const s8v*)&sB[p][(48 + col) * 32 + quad * 8];
      acc[0] = __builtin_amdgcn_mfma_f32_16x16x32_bf16(af, b0, acc[0], 0, 0, 0);
      acc[1] = __builtin_amdgcn_mfma_f32_16x16x32_bf16(af, b1, acc[1], 0, 0, 0);
      acc[2] = __builtin_amdgcn_mfma_f32_16x16x32_bf16(af, b2, acc[2], 0, 0, 0);
      acc[3] = __builtin_amdgcn_mfma_f32_16x16x32_bf16(af, b3, acc[3], 0, 0, 0);
    }
  }

  int mbase = m0 + w*16 + quad*4;
  for (int nt = 0; nt < 4; ++nt) {
    int n = n0 + nt*16 + col;
    float bz = bias[n];
    for (int r = 0; r < 4; ++r) {
      float v = acc[nt][r] + bz;
      size_t idx = (size_t)(mbase + r) * N + n;
      if (MODE == MODE_RES) {
        outF[idx] = outF[idx] + v;
      } else if (MODE == MODE_GELU) {
        outB[idx] = f2bf(0.5f * v * (1.0f + erff(v * 0.70710678118f)));
      } else {
        outB[idx] = f2bf(v);
      }
    }
  }
}

__global__ __launch_bounds__(256) void gemm_qkv_kernel(
    const short* __restrict__ A, const short* __restrict__ Wt,
    const float* __restrict__ bias, float* outF, short* outB)
{ gemm_body<MODE_BF16>(A, Wt, bias, 512, 1536, outF, outB); }

__global__ __launch_bounds__(256) void gemm_o_kernel(
    const short* __restrict__ A, const short* __restrict__ Wt,
    const float* __restrict__ bias, float* outF, short* outB)
{ gemm_body64<MODE_RES>(A, Wt, bias, 512, 512, outF, outB); }

__global__ __launch_bounds__(256) void gemm_ffn1_kernel(
    const short* __restrict__ A, const short* __restrict__ Wt,
    const float* __restrict__ bias, float* outF, short* outB)
{ gemm_body<MODE_GELU>(A, Wt, bias, 512, 2048, outF, outB); }

__global__ __launch_bounds__(256) void gemm_ffn2_kernel(
    const short* __restrict__ A, const short* __restrict__ Wt,
    const float* __restrict__ bias, float* outF, short* outB)
{ gemm_body64<MODE_RES>(A, Wt, bias, 2048, 512, outF, outB); }

// ---------------- V transpose: QKV V-part (b,s,h,hd) -> Vt (b,h,hd,s) ------
__global__ __launch_bounds__(256) void vtrans_kernel(const short* __restrict__ QKV,
                                                     short* __restrict__ Vt)
{
  __shared__ short t[64 * 72];
  int tid = threadIdx.x;
  int s0 = blockIdx.x * 64, bh = blockIdx.y;
  int b = bh >> 3, h = bh & 7;
  for (int it = 0; it < 2; ++it) {
    int c = it * 256 + tid;
    int sR = c >> 3, hc = c & 7;
    s8v v = *(const s8v*)(QKV + (size_t)(b*S_ + s0 + sR) * 1536 + 1024 + h*64 + hc*8);
    *(s8v*)&t[sR * 72 + hc * 8] = v;
  }
  __syncthreads();
  for (int it = 0; it < 2; ++it) {
    int c = it * 256 + tid;
    int hd = c >> 3, sc = c & 7;
    s8v v;
    for (int j = 0; j < 8; ++j) v[j] = t[(sc*8 + j) * 72 + hd];
    *(s8v*)(Vt + (size_t)(bh*64 + hd) * S_ + s0 + sc*8) = v;
  }
}

// ---------------- flash attention v10 (verified round-23: ~39us) -----------
// Wave-team K-split: (4 qg of 32 rows) x (2 k-teams of 32). Byte-identical
// to round-23. Flash is considered at its structural floor (~39-40us across
// three rewrites); remaining effort goes to the GEMM side.
#define SM2(ST, Ba, Bb, Bc, Bd, LS, slotQ, kpos) do {               \
    float p0 = exp2fast(ST[0] + Ba);                                \
    float p1 = exp2fast(ST[1] + Bb);                                \
    float p2 = exp2fast(ST[2] + Bc);                                \
    float p3 = exp2fast(ST[3] + Bd);                                \
    LS += (p0 + p1) + (p2 + p3);                                    \
    int2 pk;                                                        \
    pk.x = cvt_pk_bf16(p0, p1);                                     \
    pk.y = cvt_pk_bf16(p2, p3);                                     \
    *(int2*)&sAll[10240 + w*1280 + (slotQ)*640 + col*40 + (kpos) + quad*4] = pk; \
  } while (0)

#define MFMA16(A, Bv, C) C = __builtin_amdgcn_mfma_f32_16x16x32_bf16(A, Bv, C, 0, 0, 0)

__global__ __launch_bounds__(512) void flash_kernel(
    const short* __restrict__ QKV, const short* __restrict__ Vt,
    const float* __restrict__ tabT, short* __restrict__ AO)
{
  __shared__ __attribute__((aligned(16))) short sAll[20480];
  __shared__ float sRowA[256];   // [team2][qg4][qg2'2][16]

  const int tid = threadIdx.x;
  const int w = tid >> 6, lane = tid & 63;
  const int col = lane & 15, quad = lane >> 4;
  const int team = w >> 2, qg = w & 3;
  const int qbase = qg * 32;
  const int bh = blockIdx.x, qt = blockIdx.y;
  const int b = bh >> 3, h = bh & 7;
  const int q0 = qt * 128;
  const int nkt = S_ / 64;
  const float* tabh = tabT + (size_t)h * NREL_;
  const float* tbB = tabh + (OFF_ - q0 - qbase - col + team*32 + quad*4);

  const short* gQ0 = QKV + (size_t)(b*S_ + q0 + qbase + col) * 1536 + h*64 + quad*8;
  s8v bQ00 = *(const s8v*)gQ0;
  s8v bQ01 = *(const s8v*)(gQ0 + 32);
  const short* gQ1 = gQ0 + 16*1536;
  s8v bQ10 = *(const s8v*)gQ1;
  s8v bQ11 = *(const s8v*)(gQ1 + 32);

  const int c4 = tid & 3;
  const int kK = (tid >> 2) & 63, hcK = tid >> 8;
  const short* gK = QKV + (size_t)(b*S_ + kK) * 1536 + 512 + h*64 + hcK*32 + c4*8;
  short* dK = &sAll[(kK >> 5)*2560 + hcK*1280 + (kK & 31)*40 + c4*8];
  const int c8 = tid & 7, hdV = tid >> 3;
  const short* gV = Vt + (size_t)(bh*64 + hdV) * S_ + c8*8;
  short* dV = &sAll[5120 + (c8 >> 2)*2560 + hdV*40 + (c8 & 3)*8];

  int4 rk = *(const int4*)gK;
  int4 rv = *(const int4*)gV;

  float lsum0 = 0.0f, lsum1 = 0.0f;
  f4v o00 = {}, o01 = {}, o02 = {}, o03 = {};
  f4v o10 = {}, o11 = {}, o12 = {}, o13 = {};

  const int kofs = team * 2560;
  const int vofs = 5120 + team * 2560;

  for (int kt = 0; kt < nkt; ++kt) {
    const float* tb = tbB + kt * 64;
    float bm0 = tb[-16], bm1 = tb[-15], bm2 = tb[-14], bm3 = tb[-13];
    float b00 = tb[0],   b01 = tb[1],   b02 = tb[2],   b03 = tb[3];
    float bp0 = tb[16],  bp1 = tb[17],  bp2 = tb[18],  bp3 = tb[19];
    __syncthreads();
    *(int4*)dK = rk;
    *(int4*)dV = rv;
    __syncthreads();
    if (kt + 1 < nkt) {
      rk = *(const int4*)(gK + (size_t)(kt + 1) * 64 * 1536);
      rv = *(const int4*)(gV + (kt + 1) * 64);
    }
    s8v ak00 = *(const s8v*)&sAll[kofs + 0*1280 + ( 0 + col)*40 + quad*8];
    s8v ak01 = *(const s8v*)&sAll[kofs + 1*1280 + ( 0 + col)*40 + quad*8];
    s8v ak10 = *(const s8v*)&sAll[kofs + 0*1280 + (16 + col)*40 + quad*8];
    s8v ak11 = *(const s8v*)&sAll[kofs + 1*1280 + (16 + col)*40 + quad*8];
    f4v st00 = {}, st01 = {}, st10 = {}, st11 = {};
    MFMA16(ak00, bQ00, st00); MFMA16(ak01, bQ01, st00);
    MFMA16(ak00, bQ10, st01); MFMA16(ak01, bQ11, st01);
    MFMA16(ak10, bQ00, st10); MFMA16(ak11, bQ01, st10);
    MFMA16(ak10, bQ10, st11); MFMA16(ak11, bQ11, st11);
    SM2(st00, b00, b01, b02, b03, lsum0, 0, 0);
    SM2(st01, bm0, bm1, bm2, bm3, lsum1, 1, 0);
    SM2(st10, bp0, bp1, bp2, bp3, lsum0, 0, 16);
    SM2(st11, b00, b01, b02, b03, lsum1, 1, 16);
    s8v aP0 = *(const s8v*)&sAll[10240 + w*1280 +   0 + col*40 + quad*8];
    s8v aP1 = *(const s8v*)&sAll[10240 + w*1280 + 640 + col*40 + quad*8];
    s8v bv0 = *(const s8v*)&sAll[vofs + ( 0 + col)*40 + quad*8];
    s8v bv1 = *(const s8v*)&sAll[vofs + (16 + col)*40 + quad*8];
    s8v bv2 = *(const s8v*)&sAll[vofs + (32 + col)*40 + quad*8];
    s8v bv3 = *(const s8v*)&sAll[vofs + (48 + col)*40 + quad*8];
    MFMA16(aP0, bv0, o00); MFMA16(aP0, bv1, o01);
    MFMA16(aP0, bv2, o02); MFMA16(aP0, bv3, o03);
    MFMA16(aP1, bv0, o10); MFMA16(aP1, bv1, o11);
    MFMA16(aP1, bv2, o12); MFMA16(aP1, bv3, o13);
  }

  lsum0 += __shfl_xor(lsum0, 16); lsum0 += __shfl_xor(lsum0, 32);
  lsum1 += __shfl_xor(lsum1, 16); lsum1 += __shfl_xor(lsum1, 32);
  __syncthreads();
  if (lane < 16) {
    sRowA[team*128 + qg*32 + lane]      = lsum0;
    sRowA[team*128 + qg*32 + 16 + lane] = lsum1;
  }
  f4v* sComb = (f4v*)sAll;
  if (team == 1) {
    sComb[(qg*8 + 0)*64 + lane] = o00;
    sComb[(qg*8 + 1)*64 + lane] = o01;
    sComb[(qg*8 + 2)*64 + lane] = o02;
    sComb[(qg*8 + 3)*64 + lane] = o03;
    sComb[(qg*8 + 4)*64 + lane] = o10;
    sComb[(qg*8 + 5)*64 + lane] = o11;
    sComb[(qg*8 + 6)*64 + lane] = o12;
    sComb[(qg*8 + 7)*64 + lane] = o13;
  }
  __syncthreads();
  if (team == 0) {
    int rbase = qg*32 + quad*4;
    float ra0 = sRowA[rbase+0] + sRowA[128+rbase+0];
    float ra1 = sRowA[rbase+1] + sRowA[128+rbase+1];
    float ra2 = sRowA[rbase+2] + sRowA[128+rbase+2];
    float ra3 = sRowA[rbase+3] + sRowA[128+rbase+3];
    float rb0 = sRowA[rbase+16+0] + sRowA[128+rbase+16+0];
    float rb1 = sRowA[rbase+16+1] + sRowA[128+rbase+16+1];
    float rb2 = sRowA[rbase+16+2] + sRowA[128+rbase+16+2];
    float rb3 = sRowA[rbase+16+3] + sRowA[128+rbase+16+3];
    short* aoRow = AO + (size_t)(b*S_ + q0 + qbase)*512 + h*64 + col;
#define WOUT(OV, qg2, nt, RA0, RA1, RA2, RA3) do {                       \
      f4v pp = OV + sComb[(qg*8 + (qg2)*4 + (nt))*64 + lane];            \
      aoRow[((qg2)*16 + quad*4 + 0)*512 + (nt)*16] = f2bf(pp[0] / RA0);  \
      aoRow[((qg2)*16 + quad*4 + 1)*512 + (nt)*16] = f2bf(pp[1] / RA1);  \
      aoRow[((qg2)*16 + quad*4 + 2)*512 + (nt)*16] = f2bf(pp[2] / RA2);  \
      aoRow[((qg2)*16 + quad*4 + 3)*512 + (nt)*16] = f2bf(pp[3] / RA3);  \
    } while (0)
    WOUT(o00, 0, 0, ra0, ra1, ra2, ra3);
    WOUT(o01, 0, 1, ra0, ra1, ra2, ra3);
    WOUT(o02, 0, 2, ra0, ra1, ra2, ra3);
    WOUT(o03, 0, 3, ra0, ra1, ra2, ra3);
    WOUT(o10, 1, 0, rb0, rb1, rb2, rb3);
    WOUT(o11, 1, 1, rb0, rb1, rb2, rb3);
    WOUT(o12, 1, 2, rb0, rb1, rb2, rb3);
    WOUT(o13, 1, 3, rb0, rb1, rb2, rb3);
#undef WOUT
  }
}

// ===========================================================================
extern "C" void kernel_launch(void* const* d_in, const int* in_sizes, int n_in,
                              void* d_out, int out_size, void* d_ws, size_t ws_size,
                              hipStream_t stream)
{
  const float* x    = (const float*)d_in[0];
  const float* f0   = (const float*)d_in[1];
  const float* sp   = (const float*)d_in[2];
  const float* ap   = (const float*)d_in[3];
  const float* spk  = (const float*)d_in[4];
  const float* Wf0  = (const float*)d_in[5];  const float* bf0  = (const float*)d_in[6];
  const float* Wsp  = (const float*)d_in[7];  const float* bsp  = (const float*)d_in[8];
  const float* Wap  = (const float*)d_in[9];  const float* bap  = (const float*)d_in[10];
  const float* Wspk = (const float*)d_in[11]; const float* bspk = (const float*)d_in[12];
  const float* Wq   = (const float*)d_in[13]; const float* bq   = (const float*)d_in[14];
  const float* Wk   = (const float*)d_in[15]; const float* bk   = (const float*)d_in[16];
  const float* Wv   = (const float*)d_in[17]; const float* bv   = (const float*)d_in[18];
  const float* Wo   = (const float*)d_in[19]; const float* bo   = (const float*)d_in[20];
  const float* ln1g = (const float*)d_in[21]; const float* ln1b = (const float*)d_in[22];
  const float* ln2g = (const float*)d_in[23]; const float* ln2b = (const float*)d_in[24];
  const float* W1   = (const float*)d_in[25]; const float* b1   = (const float*)d_in[26];
  const float* W2   = (const float*)d_in[27]; const float* b2   = (const float*)d_in[28];
  const float* tab  = (const float*)d_in[29];
  const float* gfin = (const float*)d_in[30]; const float* bfin = (const float*)d_in[31];

  char* p = (char*)d_ws;
  auto alloc = [&](size_t bytes) { char* r = p; p += (bytes + 255) & ~(size_t)255; return r; };
  short* WqkvT = (short*)alloc((size_t)L_ * 1536 * 512 * 2);
  short* WoT   = (short*)alloc((size_t)L_ * 512 * 512 * 2);
  short* W1T   = (short*)alloc((size_t)L_ * 2048 * 512 * 2);
  short* W2T   = (short*)alloc((size_t)L_ * 512 * 2048 * 2);
  float* bqkv  = (float*)alloc((size_t)L_ * 1536 * 4);
  float* X     = (float*)alloc((size_t)M_ * D_ * 4);
  short* Hb    = (short*)alloc((size_t)M_ * D_ * 2);
  short* AO    = (short*)alloc((size_t)M_ * D_ * 2);
  short* QKVb  = (short*)alloc((size_t)M_ * 1536 * 2);
  short* VtG   = (short*)alloc((size_t)B_ * H_ * HD_ * S_ * 2);
  short* H1b   = QKVb;  // alias: FFN hidden (M,F) reuses QKVb+VtG region (exactly 16 MB)
  float* sproj = (float*)alloc((size_t)B_ * D_ * 4);
  float* tabT  = (float*)alloc((size_t)L_ * H_ * NREL_ * 4);

  dim3 b256(256);
  dim3 tb(32, 8);
  packb_kernel<<<dim3((L_*1536 + 255)/256), b256, 0, stream>>>(bq, bk, bv, bqkv);
  tabt_kernel<<<dim3((L_*H_*NREL_ + 255)/256), b256, 0, stream>>>(tab, tabT);
  transpose_kernel<<<dim3(16, 16, L_), tb, 0, stream>>>(Wq, WqkvT, 512, 512, 512*512, 1536*512, 0);
  transpose_kernel<<<dim3(16, 16, L_), tb, 0, stream>>>(Wk, WqkvT, 512, 512, 512*512, 1536*512, 512);
  transpose_kernel<<<dim3(16, 16, L_), tb, 0, stream>>>(Wv, WqkvT, 512, 512, 512*512, 1536*512, 1024);
  transpose_kernel<<<dim3(16, 16, L_), tb, 0, stream>>>(Wo, WoT, 512, 512, 512*512, 512*512, 0);
  transpose_kernel<<<dim3(64, 16, L_), tb, 0, stream>>>(W1, W1T, 512, 2048, 512*2048, 2048*512, 0);
  transpose_kernel<<<dim3(16, 64, L_), tb, 0, stream>>>(W2, W2T, 2048, 512, 2048*512, 512*2048, 0);
  spk_kernel<<<dim3(B_, 8), b256, 0, stream>>>(spk, Wspk, bspk, sproj);
  prologue_kernel<<<dim3(M_), b256, 0, stream>>>(x, f0, sp, ap, Wf0, bf0, Wsp, bsp, Wap, bap, sproj, X);

  for (int l = 0; l < L_; ++l) {
    ln_kernel<<<dim3(M_), b256, 0, stream>>>(X, ln1g + l*D_, ln1b + l*D_, Hb, nullptr, 0);
    gemm_qkv_kernel<<<dim3(32, 24, 1), b256, 0, stream>>>(
        Hb, WqkvT + (size_t)l*1536*512, bqkv + l*1536, nullptr, QKVb);
    vtrans_kernel<<<dim3(S_/64, B_*H_), b256, 0, stream>>>(QKVb, VtG);
    flash_kernel<<<dim3(B_*H_, S_/128), dim3(512), 0, stream>>>(QKVb, VtG, tabT + (size_t)l*H_*NREL_, AO);
    gemm_o_kernel<<<dim3(64, 8, 1), b256, 0, stream>>>(
        AO, WoT + (size_t)l*512*512, bo + l*D_, X, nullptr);
    ln_kernel<<<dim3(M_), b256, 0, stream>>>(X, ln2g + l*D_, ln2b + l*D_, Hb, nullptr, 0);
    gemm_ffn1_kernel<<<dim3(32, 32, 1), b256, 0, stream>>>(
        Hb, W1T + (size_t)l*2048*512, b1 + l*F_, nullptr, H1b);
    gemm_ffn2_kernel<<<dim3(64, 8, 1), b256, 0, stream>>>(
        H1b, W2T + (size_t)l*512*2048, b2 + l*D_, X, nullptr);
  }
  ln_kernel<<<dim3(M_), b256, 0, stream>>>(X, gfin, bfin, nullptr, (float*)d_out, 1);
}